// Round 10
// baseline (388.191 us; speedup 1.0000x reference)
//
#include <hip/hip_runtime.h>
#include <cstdint>
#include <cstddef>

#define BB 64
#define TT 512
#define DD 1024
#define NTAG 64
#define CUT 255  // prefix handles t<=CUT, suffix t>CUT; wsA/wsB each 256 slots
#define SCORES_ELEMS (BB * TT * NTAG)      // 2097152
#define TAGS_OFF SCORES_ELEMS              // 2097152
#define LOSS_OFF (SCORES_ELEMS + BB * TT)  // 2130920

typedef __attribute__((ext_vector_type(8))) short short8;
typedef __attribute__((ext_vector_type(4))) float floatx4;
typedef __attribute__((ext_vector_type(16))) float f32x16;

__device__ __forceinline__ unsigned short f2bf_rne(float x) {
  const unsigned int u = __float_as_uint(x);
  const unsigned int r = u + 0x7FFFu + ((u >> 16) & 1u);
  return (unsigned short)(r >> 16);
}
__device__ __forceinline__ float bf2f(unsigned short h) {
  return __uint_as_float(((unsigned int)h) << 16);
}

// Raw barrier: LDS-ordering only (no vmcnt drain; alpha/beta stores stay
// in flight across steps, nothing ever waits on them).
__device__ __forceinline__ void block_sync_lds() {
  asm volatile("s_waitcnt lgkmcnt(0)\n\ts_barrier" ::: "memory");
}

// quad_perm DPP: exchange with lane^1 / lane^2 (cross-chunk reduce partners)
__device__ __forceinline__ float quad_xor1(float v) {
  int x = __builtin_amdgcn_update_dpp(__float_as_int(v), __float_as_int(v), 0xB1, 0xf, 0xf, false);
  return __int_as_float(x);
}
__device__ __forceinline__ float quad_xor2(float v) {
  int x = __builtin_amdgcn_update_dpp(__float_as_int(v), __float_as_int(v), 0x4E, 0xf, 0xf, false);
  return __int_as_float(x);
}

// ---------------- DPP wave64 reductions ----------------
__device__ __forceinline__ float dpp_red_max(float v) {
  int x;
  x = __builtin_amdgcn_update_dpp(__float_as_int(v), __float_as_int(v), 0x111, 0xf, 0xf, false);
  v = fmaxf(v, __int_as_float(x));
  x = __builtin_amdgcn_update_dpp(__float_as_int(v), __float_as_int(v), 0x112, 0xf, 0xf, false);
  v = fmaxf(v, __int_as_float(x));
  x = __builtin_amdgcn_update_dpp(__float_as_int(v), __float_as_int(v), 0x114, 0xf, 0xf, false);
  v = fmaxf(v, __int_as_float(x));
  x = __builtin_amdgcn_update_dpp(__float_as_int(v), __float_as_int(v), 0x118, 0xf, 0xf, false);
  v = fmaxf(v, __int_as_float(x));
  x = __builtin_amdgcn_update_dpp(__float_as_int(v), __float_as_int(v), 0x142, 0xa, 0xf, false);
  v = fmaxf(v, __int_as_float(x));
  x = __builtin_amdgcn_update_dpp(__float_as_int(v), __float_as_int(v), 0x143, 0xc, 0xf, false);
  v = fmaxf(v, __int_as_float(x));
  return __int_as_float(__builtin_amdgcn_readlane(__float_as_int(v), 63));
}

__device__ __forceinline__ float dpp_red_sum(float v) {
  int x;
  x = __builtin_amdgcn_update_dpp(__float_as_int(v), __float_as_int(v), 0x111, 0xf, 0xf, false);
  v = v + __int_as_float(x);
  x = __builtin_amdgcn_update_dpp(__float_as_int(v), __float_as_int(v), 0x112, 0xf, 0xf, false);
  v = v + __int_as_float(x);
  x = __builtin_amdgcn_update_dpp(__float_as_int(v), __float_as_int(v), 0x114, 0xf, 0xf, false);
  v = v + __int_as_float(x);
  x = __builtin_amdgcn_update_dpp(__float_as_int(v), __float_as_int(v), 0x118, 0xf, 0xf, false);
  v = v + __int_as_float(x);
  x = __builtin_amdgcn_update_dpp(__float_as_int(v), __float_as_int(v), 0x142, 0xa, 0xf, false);
  v = v + __int_as_float(x);
  x = __builtin_amdgcn_update_dpp(__float_as_int(v), __float_as_int(v), 0x143, 0xc, 0xf, false);
  v = v + __int_as_float(x);
  return __int_as_float(__builtin_amdgcn_readlane(__float_as_int(v), 63));
}

// ---------------- Kernel 0: W -> bf16 hi/lo fragments (B-operand order) ----
__global__ __launch_bounds__(256) void prep_w(
    const float* __restrict__ W, unsigned short* __restrict__ wf_hi,
    unsigned short* __restrict__ wf_lo) {
  const int f = blockIdx.x * 256 + threadIdx.x;  // 0..8191
  const int kk = f >> 8;
  const int nt = (f >> 6) & 3;
  const int l = f & 63;
  const int n = nt * 16 + (l & 15);
  const int k0 = kk * 32 + ((l >> 4) << 3);
  short8 hv, lv;
#pragma unroll
  for (int j = 0; j < 8; ++j) {
    const float x = W[(size_t)(k0 + j) * NTAG + n];
    const unsigned short h = f2bf_rne(x);
    hv[j] = (short)h;
    lv[j] = (short)f2bf_rne(x - bf2f(h));
  }
  *reinterpret_cast<short8*>(wf_hi + (size_t)f * 8) = hv;
  *reinterpret_cast<short8*>(wf_lo + (size_t)f * 8) = lv;
}

// ---------------- Kernel 1: scores = (X @ W + b) * mask  (MFMA) ----------
// v7.1 barrier-free split-K + register double-buffer of A and B.
__global__ __launch_bounds__(256, 4) void gemm_scores(
    const float* __restrict__ X, const int* __restrict__ mask,
    const unsigned short* __restrict__ wf_hi,
    const unsigned short* __restrict__ wf_lo,
    const float* __restrict__ bias, float* __restrict__ scores) {
  __shared__ float red[3 * 64 * 17];  // [wave-1][lane][16 acc vals], pad 17
  const int tid = threadIdx.x;
  const int lane = tid & 63;
  const int wv = tid >> 6;           // K-quarter id
  const int row0 = blockIdx.x * 16;  // output row tile
  const int arow = row0 + (lane & 15);
  const int aq = (lane >> 4) << 3;   // k sub-offset 0,8,16,24
  const float* Ap = X + (size_t)arow * DD + wv * 256 + aq;

  floatx4 acc[4];
#pragma unroll
  for (int nt = 0; nt < 4; ++nt) acc[nt] = (floatx4)(0.f);

  // prefetch A chunk 0
  float4 a0 = *reinterpret_cast<const float4*>(Ap);
  float4 a1 = *reinterpret_cast<const float4*>(Ap + 4);

  // prefetch B chunk 0
  short8 cbh[4], cbl[4];
  {
    const size_t fbase0 = (size_t)(wv * 8) * 4 * 64 * 8;
#pragma unroll
    for (int nt = 0; nt < 4; ++nt) {
      const size_t off = fbase0 + ((size_t)nt * 64 + lane) * 8;
      cbh[nt] = *reinterpret_cast<const short8*>(wf_hi + off);
      cbl[nt] = *reinterpret_cast<const short8*>(wf_lo + off);
    }
  }

#pragma unroll
  for (int kk = 0; kk < 8; ++kk) {
    short8 ah, al;
    {
      const float v[8] = {a0.x, a0.y, a0.z, a0.w, a1.x, a1.y, a1.z, a1.w};
#pragma unroll
      for (int e = 0; e < 8; ++e) {
        const unsigned short h = f2bf_rne(v[e]);
        ah[e] = (short)h;
        al[e] = (short)f2bf_rne(v[e] - bf2f(h));
      }
    }
    // prefetch A + B for chunk kk+1 (hidden under this chunk's MFMAs)
    short8 nbh[4], nbl[4];
    if (kk < 7) {
      a0 = *reinterpret_cast<const float4*>(Ap + (kk + 1) * 32);
      a1 = *reinterpret_cast<const float4*>(Ap + (kk + 1) * 32 + 4);
      const size_t fbaseN = (size_t)(wv * 8 + kk + 1) * 4 * 64 * 8;
#pragma unroll
      for (int nt = 0; nt < 4; ++nt) {
        const size_t off = fbaseN + ((size_t)nt * 64 + lane) * 8;
        nbh[nt] = *reinterpret_cast<const short8*>(wf_hi + off);
        nbl[nt] = *reinterpret_cast<const short8*>(wf_lo + off);
      }
    }
#pragma unroll
    for (int nt = 0; nt < 4; ++nt) {
      acc[nt] = __builtin_amdgcn_mfma_f32_16x16x32_bf16(ah, cbh[nt], acc[nt], 0, 0, 0);
      acc[nt] = __builtin_amdgcn_mfma_f32_16x16x32_bf16(ah, cbl[nt], acc[nt], 0, 0, 0);
      acc[nt] = __builtin_amdgcn_mfma_f32_16x16x32_bf16(al, cbh[nt], acc[nt], 0, 0, 0);
    }
    if (kk < 7) {
#pragma unroll
      for (int nt = 0; nt < 4; ++nt) { cbh[nt] = nbh[nt]; cbl[nt] = nbl[nt]; }
    }
  }

  if (wv > 0) {
    float* dst = &red[((wv - 1) * 64 + lane) * 17];
#pragma unroll
    for (int nt = 0; nt < 4; ++nt)
#pragma unroll
      for (int r = 0; r < 4; ++r) dst[nt * 4 + r] = acc[nt][r];
  }
  __syncthreads();
  if (wv == 0) {
#pragma unroll
    for (int w = 0; w < 3; ++w) {
      const float* srcp = &red[(w * 64 + lane) * 17];
#pragma unroll
      for (int nt = 0; nt < 4; ++nt)
#pragma unroll
        for (int r = 0; r < 4; ++r) acc[nt][r] += srcp[nt * 4 + r];
    }
    const int colb = lane & 15;
    const int quad = lane >> 4;
#pragma unroll
    for (int r = 0; r < 4; ++r) {
      const int row = row0 + quad * 4 + r;
      const float mf = (float)mask[row];
#pragma unroll
      for (int nt = 0; nt < 4; ++nt) {
        const int col = nt * 16 + colb;
        scores[(size_t)row * 64 + col] = (acc[nt][r] + bias[col]) * mf;
      }
    }
  }
}

// ---------------- Kernel 2: forward+backward passes (4-wave cooperative) --
// v9: ZERO global loads in the serial loop. Per-step cost was pinned at
// ~785 cyc across all prior structures; visible chain is only ~300 cyc.
// Culprit: in-loop global loads (emission prefetch + mask) mixed with 16
// fire-and-forget alpha/beta stores in the same vmcnt queue -> the
// compiler's load-use s_waitcnt stalls each step on prior stores. Fix:
// preload the block's emission slab (256x64 fp32, in two 32KB halves) and
// mask range into LDS up front; in-loop memory = LDS reads + global stores
// that nothing waits on. e0..e3/k0..k3 shift machinery deleted.
__global__ __launch_bounds__(256, 1) void crf_forward(
    const float* __restrict__ scores, const int* __restrict__ mask,
    const float* __restrict__ trans, const float* __restrict__ startv,
    const float* __restrict__ endv, float* __restrict__ ws_alpha,
    float* __restrict__ ws_beta, float* __restrict__ zAcut,
    float* __restrict__ bScut, float* __restrict__ bVcut,
    float* __restrict__ Ca, float* __restrict__ Cb) {
  __shared__ float lds_e[128 * NTAG];  // 32KB emission half-slab
  __shared__ int lds_mk[256];
  __shared__ float zbuf[2][NTAG];  // broadcast buffer
  __shared__ float part[4];        // cross-wave partials
  const int tid = threadIdx.x;
  const int wv = tid >> 6;     // wave id = output block
  const int lane = tid & 63;
  const int q = lane & 3;      // source chunk id (k in [16q,16q+16))
  const int jl = lane >> 2;    // 0..15
  const int j = wv * 16 + jl;  // owned output tag
  const int role = blockIdx.x >> 6;
  const int b = blockIdx.x & 63;
  const float* sc = scores + (size_t)b * TT * NTAG;
  const int* maskb = mask + b * TT;
  const int t0 = (role >= 2) ? 256 : 0;

  auto preload = [&](int h) {  // load emissions t in [t0+128h, t0+128h+128)
    const float4* src = reinterpret_cast<const float4*>(sc + (size_t)(t0 + 128 * h) * NTAG);
    float4* dst = reinterpret_cast<float4*>(lds_e);
#pragma unroll
    for (int it = 0; it < 8; ++it) dst[tid + it * 256] = src[tid + it * 256];
  };

  lds_mk[tid] = maskb[t0 + tid];
  preload(role >= 2 ? 1 : 0);
  __syncthreads();

  if (role == 0) {
    // ---- forward Viterbi (max-plus), t = 1..CUT ----
    f32x16 tc;  // tc[i2] = trans[16q+i2][j]  (column chunk)
#pragma unroll
    for (int i2 = 0; i2 < 16; ++i2)
      tc[i2] = trans[(size_t)(16 * q + i2) * NTAG + j];

    float aj = startv[j] + lds_e[j];  // alpha_0[j] (e_0)
    if (q == 0) zbuf[0][j] = aj;
    float* wsA = ws_alpha + (size_t)b * 256 * NTAG;
    __syncthreads();

    int cur = 0;
#pragma unroll 1
    for (int half = 0; half < 2; ++half) {
      const int tlo = (half == 0) ? 1 : 128;
      const int thi = (half == 0) ? 127 : 255;
      for (int t = tlo; t <= thi; ++t) {
        if (q == 0) wsA[(size_t)(t - 1) * NTAG + j] = aj;  // fire-and-forget
        const float4 a0 = *reinterpret_cast<const float4*>(&zbuf[cur][q * 16 + 0]);
        const float4 a1 = *reinterpret_cast<const float4*>(&zbuf[cur][q * 16 + 4]);
        const float4 a2 = *reinterpret_cast<const float4*>(&zbuf[cur][q * 16 + 8]);
        const float4 a3 = *reinterpret_cast<const float4*>(&zbuf[cur][q * 16 + 12]);
        const float e = lds_e[(t - 128 * half) * NTAG + j];
        const int m = lds_mk[t];

        const float c0 = a0.x + tc[0],  c1 = a0.y + tc[1];
        const float c2 = a0.z + tc[2],  c3 = a0.w + tc[3];
        const float c4 = a1.x + tc[4],  c5 = a1.y + tc[5];
        const float c6 = a1.z + tc[6],  c7 = a1.w + tc[7];
        const float c8 = a2.x + tc[8],  c9 = a2.y + tc[9];
        const float cA = a2.z + tc[10], cB = a2.w + tc[11];
        const float cC = a3.x + tc[12], cD = a3.y + tc[13];
        const float cE = a3.z + tc[14], cF = a3.w + tc[15];
        const float h0 = fmaxf(fmaxf(c0, c1), fmaxf(c2, c3));
        const float h1 = fmaxf(fmaxf(c4, c5), fmaxf(c6, c7));
        const float h2 = fmaxf(fmaxf(c8, c9), fmaxf(cA, cB));
        const float h3 = fmaxf(fmaxf(cC, cD), fmaxf(cE, cF));
        float pm = fmaxf(fmaxf(h0, h1), fmaxf(h2, h3));
        pm = fmaxf(pm, quad_xor1(pm));
        pm = fmaxf(pm, quad_xor2(pm));

        aj = m ? (pm + e) : aj;
        const int nxt = cur ^ 1;
        if (q == 0) zbuf[nxt][j] = aj;
        block_sync_lds();
        cur = nxt;
      }
      if (half == 0) { preload(1); __syncthreads(); }
    }
    if (q == 0) wsA[(size_t)255 * NTAG + j] = aj;  // alpha_CUT
  } else if (role == 1) {
    // ---- forward sum-product (linear domain, periodic renorm), t=1..CUT --
    f32x16 ec;  // ec[i2] = exp(trans[16q+i2][j])
#pragma unroll
    for (int i2 = 0; i2 < 16; ++i2)
      ec[i2] = expf(trans[(size_t)(16 * q + i2) * NTAG + j]);

    const float a0v = startv[j] + lds_e[j];
    const float wm = dpp_red_max(a0v);
    if (lane == 0) part[wv] = wm;
    __syncthreads();
    const float M0 = fmaxf(fmaxf(part[0], part[1]), fmaxf(part[2], part[3]));
    float zj = expf(a0v - M0);
    float C = M0;
    if (q == 0) zbuf[0][j] = zj;
    __syncthreads();

    int cur = 0;
#pragma unroll 1
    for (int half = 0; half < 2; ++half) {
      const int tlo = (half == 0) ? 1 : 128;
      const int thi = (half == 0) ? 127 : 255;
      for (int t = tlo; t <= thi; ++t) {
        const float4 z0 = *reinterpret_cast<const float4*>(&zbuf[cur][q * 16 + 0]);
        const float4 z1 = *reinterpret_cast<const float4*>(&zbuf[cur][q * 16 + 4]);
        const float4 z2 = *reinterpret_cast<const float4*>(&zbuf[cur][q * 16 + 8]);
        const float4 z3 = *reinterpret_cast<const float4*>(&zbuf[cur][q * 16 + 12]);
        const float e = lds_e[(t - 128 * half) * NTAG + j];
        const int m = lds_mk[t];
        const float pec = expf(e);

        float s0 = z0.x * ec[0], s1 = z0.y * ec[1];
        float s2 = z0.z * ec[2], s3 = z0.w * ec[3];
        s0 = fmaf(z1.x, ec[4], s0);  s1 = fmaf(z1.y, ec[5], s1);
        s2 = fmaf(z1.z, ec[6], s2);  s3 = fmaf(z1.w, ec[7], s3);
        s0 = fmaf(z2.x, ec[8], s0);  s1 = fmaf(z2.y, ec[9], s1);
        s2 = fmaf(z2.z, ec[10], s2); s3 = fmaf(z2.w, ec[11], s3);
        s0 = fmaf(z3.x, ec[12], s0); s1 = fmaf(z3.y, ec[13], s1);
        s2 = fmaf(z3.z, ec[14], s2); s3 = fmaf(z3.w, ec[15], s3);
        float s = (s0 + s1) + (s2 + s3);
        s += quad_xor1(s);
        s += quad_xor2(s);

        zj = m ? (s * pec) : zj;

        if ((t & 7) == 0) {
          const float ws = dpp_red_sum(zj);  // = 4 * per-wave sum
          if (lane == 0) part[wv] = ws;
          block_sync_lds();
          const float S4 = (part[0] + part[1]) + (part[2] + part[3]);
          const float r = __builtin_amdgcn_rcpf(S4);
          zj *= 4.0f * r;
          C += logf(S4) - 1.3862943611198906f;
        }

        const int nxt = cur ^ 1;
        if (q == 0) zbuf[nxt][j] = zj;
        block_sync_lds();
        cur = nxt;
      }
      if (half == 0) { preload(1); __syncthreads(); }
    }
    if (q == 0) zAcut[b * NTAG + j] = zj;
    if (tid == 0) Ca[b] = C;
  } else if (role == 2) {
    // ---- backward Viterbi (max-plus), t = 511..256 ----
    f32x16 tc;  // ROW chunk: tc[i2] = trans[j][16q+i2] (contiguous)
#pragma unroll
    for (int i2 = 0; i2 < 16; ++i2)
      tc[i2] = trans[(size_t)j * NTAG + 16 * q + i2];

    float bj = endv[j];  // betaV_511
    float* wsB = ws_beta + (size_t)b * 256 * NTAG;
    if (q == 0) {
      wsB[(size_t)255 * NTAG + j] = bj;               // betaV_511
      zbuf[0][j] = bj + lds_e[127 * NTAG + j];        // h_511 (e_511)
    }
    __syncthreads();

    int cur = 0;
#pragma unroll 1
    for (int half = 1; half >= 0; --half) {
      const int thi = (half == 1) ? 511 : 384;
      const int tlo = (half == 1) ? 385 : 257;
      const int ebase = 256 + 128 * half;  // slab covers e[ebase..ebase+128)
      for (int t = thi; t >= tlo; --t) {
        const float4 a0 = *reinterpret_cast<const float4*>(&zbuf[cur][q * 16 + 0]);
        const float4 a1 = *reinterpret_cast<const float4*>(&zbuf[cur][q * 16 + 4]);
        const float4 a2 = *reinterpret_cast<const float4*>(&zbuf[cur][q * 16 + 8]);
        const float4 a3 = *reinterpret_cast<const float4*>(&zbuf[cur][q * 16 + 12]);
        const float e = lds_e[(t - 1 - ebase) * NTAG + j];  // e_{t-1}
        const int m = lds_mk[t - 256];                      // m_t

        const float c0 = a0.x + tc[0],  c1 = a0.y + tc[1];
        const float c2 = a0.z + tc[2],  c3 = a0.w + tc[3];
        const float c4 = a1.x + tc[4],  c5 = a1.y + tc[5];
        const float c6 = a1.z + tc[6],  c7 = a1.w + tc[7];
        const float c8 = a2.x + tc[8],  c9 = a2.y + tc[9];
        const float cA = a2.z + tc[10], cB = a2.w + tc[11];
        const float cC = a3.x + tc[12], cD = a3.y + tc[13];
        const float cE = a3.z + tc[14], cF = a3.w + tc[15];
        const float h0 = fmaxf(fmaxf(c0, c1), fmaxf(c2, c3));
        const float h1 = fmaxf(fmaxf(c4, c5), fmaxf(c6, c7));
        const float h2 = fmaxf(fmaxf(c8, c9), fmaxf(cA, cB));
        const float h3 = fmaxf(fmaxf(cC, cD), fmaxf(cE, cF));
        float pm = fmaxf(fmaxf(h0, h1), fmaxf(h2, h3));
        pm = fmaxf(pm, quad_xor1(pm));
        pm = fmaxf(pm, quad_xor2(pm));

        bj = m ? pm : bj;  // betaV_{t-1}
        const int nxt = cur ^ 1;
        if (q == 0) {
          wsB[(size_t)(t - 257) * NTAG + j] = bj;  // betaV_{t-1}, idx 254..0
          zbuf[nxt][j] = bj + e;                   // h_{t-1}
        }
        block_sync_lds();
        cur = nxt;
      }
      if (half == 1) { preload(0); __syncthreads(); }
    }
    // epilogue t=256 -> betaV_255 (m_256 = lds_mk[0]; h_256 in zbuf[cur])
    {
      const float4 a0 = *reinterpret_cast<const float4*>(&zbuf[cur][q * 16 + 0]);
      const float4 a1 = *reinterpret_cast<const float4*>(&zbuf[cur][q * 16 + 4]);
      const float4 a2 = *reinterpret_cast<const float4*>(&zbuf[cur][q * 16 + 8]);
      const float4 a3 = *reinterpret_cast<const float4*>(&zbuf[cur][q * 16 + 12]);
      const int m = lds_mk[0];
      const float c0 = a0.x + tc[0],  c1 = a0.y + tc[1];
      const float c2 = a0.z + tc[2],  c3 = a0.w + tc[3];
      const float c4 = a1.x + tc[4],  c5 = a1.y + tc[5];
      const float c6 = a1.z + tc[6],  c7 = a1.w + tc[7];
      const float c8 = a2.x + tc[8],  c9 = a2.y + tc[9];
      const float cA = a2.z + tc[10], cB = a2.w + tc[11];
      const float cC = a3.x + tc[12], cD = a3.y + tc[13];
      const float cE = a3.z + tc[14], cF = a3.w + tc[15];
      const float h0 = fmaxf(fmaxf(c0, c1), fmaxf(c2, c3));
      const float h1 = fmaxf(fmaxf(c4, c5), fmaxf(c6, c7));
      const float h2 = fmaxf(fmaxf(c8, c9), fmaxf(cA, cB));
      const float h3 = fmaxf(fmaxf(cC, cD), fmaxf(cE, cF));
      float pm = fmaxf(fmaxf(h0, h1), fmaxf(h2, h3));
      pm = fmaxf(pm, quad_xor1(pm));
      pm = fmaxf(pm, quad_xor2(pm));
      bj = m ? pm : bj;  // betaV_255
      if (q == 0) bVcut[b * NTAG + j] = bj;
    }
  } else {
    // ---- backward sum-product, t = 511..256 ----
    f32x16 ec;  // ROW chunk: ec[i2] = exp(trans[j][16q+i2])
#pragma unroll
    for (int i2 = 0; i2 < 16; ++i2)
      ec[i2] = expf(trans[(size_t)j * NTAG + 16 * q + i2]);

    float bj = expf(endv[j]);  // bLin_511
    float C = 0.f;
    if (q == 0) zbuf[0][j] = bj * expf(lds_e[127 * NTAG + j]);  // g_511
    __syncthreads();

    int cur = 0;
#pragma unroll 1
    for (int half = 1; half >= 0; --half) {
      const int thi = (half == 1) ? 511 : 384;
      const int tlo = (half == 1) ? 385 : 257;
      const int ebase = 256 + 128 * half;
      for (int t = thi; t >= tlo; --t) {
        const float4 z0 = *reinterpret_cast<const float4*>(&zbuf[cur][q * 16 + 0]);
        const float4 z1 = *reinterpret_cast<const float4*>(&zbuf[cur][q * 16 + 4]);
        const float4 z2 = *reinterpret_cast<const float4*>(&zbuf[cur][q * 16 + 8]);
        const float4 z3 = *reinterpret_cast<const float4*>(&zbuf[cur][q * 16 + 12]);
        const float e = lds_e[(t - 1 - ebase) * NTAG + j];  // e_{t-1}
        const int m = lds_mk[t - 256];                      // m_t
        const float pec = expf(e);

        float s0 = z0.x * ec[0], s1 = z0.y * ec[1];
        float s2 = z0.z * ec[2], s3 = z0.w * ec[3];
        s0 = fmaf(z1.x, ec[4], s0);  s1 = fmaf(z1.y, ec[5], s1);
        s2 = fmaf(z1.z, ec[6], s2);  s3 = fmaf(z1.w, ec[7], s3);
        s0 = fmaf(z2.x, ec[8], s0);  s1 = fmaf(z2.y, ec[9], s1);
        s2 = fmaf(z2.z, ec[10], s2); s3 = fmaf(z2.w, ec[11], s3);
        s0 = fmaf(z3.x, ec[12], s0); s1 = fmaf(z3.y, ec[13], s1);
        s2 = fmaf(z3.z, ec[14], s2); s3 = fmaf(z3.w, ec[15], s3);
        float s = (s0 + s1) + (s2 + s3);
        s += quad_xor1(s);
        s += quad_xor2(s);

        bj = m ? s : bj;  // bLin_{t-1}

        if ((t & 7) == 0) {
          const float ws = dpp_red_sum(bj);
          if (lane == 0) part[wv] = ws;
          block_sync_lds();
          const float S4 = (part[0] + part[1]) + (part[2] + part[3]);
          const float r = __builtin_amdgcn_rcpf(S4);
          bj *= 4.0f * r;
          C += logf(S4) - 1.3862943611198906f;
        }

        const int nxt = cur ^ 1;
        if (q == 0) zbuf[nxt][j] = bj * pec;  // g_{t-1}
        block_sync_lds();
        cur = nxt;
      }
      if (half == 1) { preload(0); __syncthreads(); }
    }
    // epilogue t=256 -> bLin_255 (m_256 = lds_mk[0])
    {
      const float4 z0 = *reinterpret_cast<const float4*>(&zbuf[cur][q * 16 + 0]);
      const float4 z1 = *reinterpret_cast<const float4*>(&zbuf[cur][q * 16 + 4]);
      const float4 z2 = *reinterpret_cast<const float4*>(&zbuf[cur][q * 16 + 8]);
      const float4 z3 = *reinterpret_cast<const float4*>(&zbuf[cur][q * 16 + 12]);
      const int m = lds_mk[0];
      float s0 = z0.x * ec[0], s1 = z0.y * ec[1];
      float s2 = z0.z * ec[2], s3 = z0.w * ec[3];
      s0 = fmaf(z1.x, ec[4], s0);  s1 = fmaf(z1.y, ec[5], s1);
      s2 = fmaf(z1.z, ec[6], s2);  s3 = fmaf(z1.w, ec[7], s3);
      s0 = fmaf(z2.x, ec[8], s0);  s1 = fmaf(z2.y, ec[9], s1);
      s2 = fmaf(z2.z, ec[10], s2); s3 = fmaf(z2.w, ec[11], s3);
      s0 = fmaf(z3.x, ec[12], s0); s1 = fmaf(z3.y, ec[13], s1);
      s2 = fmaf(z3.z, ec[14], s2); s3 = fmaf(z3.w, ec[15], s3);
      float s = (s0 + s1) + (s2 + s3);
      s += quad_xor1(s);
      s += quad_xor2(s);
      bj = m ? s : bj;  // bLin_255
      if (q == 0) bScut[b * NTAG + j] = bj;
      if (tid == 0) Cb[b] = C;
    }
  }
}

// ---------------- Kernel 2b: combine at the cut ----------------
__global__ __launch_bounds__(64, 1) void crf_combine(
    const float* __restrict__ scores, const int* __restrict__ mask,
    const int* __restrict__ labels, const float* __restrict__ trans,
    const float* __restrict__ startv, const float* __restrict__ endv,
    const float* __restrict__ ws_alpha, const float* __restrict__ bVcut,
    const float* __restrict__ zAcut, const float* __restrict__ bScut,
    const float* __restrict__ Ca, const float* __restrict__ Cb,
    int* __restrict__ ws_lasttag, float* __restrict__ ws_loss) {
  const int lane = threadIdx.x;
  const int b = blockIdx.x;
  const float* sc = scores + (size_t)b * TT * NTAG;
  const int* maskb = mask + b * TT;

  // Viterbi cut tag
  const float aV = ws_alpha[((size_t)b * 256 + 255) * NTAG + lane];
  const float fv = aV + bVcut[b * NTAG + lane];
  const float mx = dpp_red_max(fv);
  const int jstar = (int)__builtin_ctzll(__ballot(fv == mx));
  if (lane == 0) ws_lasttag[b] = jstar;

  // log Z
  const float S = dpp_red_sum(zAcut[b * NTAG + lane] * bScut[b * NTAG + lane]);
  const float log_z = logf(S) + Ca[b] + Cb[b];

  // gold score
  float g = 0.f, msumf = 0.f;
  for (int t = lane; t < TT; t += 64) {
    const int lab = labels[b * TT + t];
    const float mf = (float)maskb[t];
    msumf += mf;
    g += sc[(size_t)t * NTAG + lab] * mf;
    if (t >= 1) {
      const int labp = labels[b * TT + t - 1];
      g += trans[(size_t)labp * NTAG + lab] * mf;
    }
  }
  g = dpp_red_sum(g);
  const float msum = dpp_red_sum(msumf);
  const int last_idx = (int)msum - 1;
  g += startv[labels[b * TT]] + endv[labels[b * TT + last_idx]];
  if (lane == 0) ws_loss[b] = log_z - g;
}

// ---------------- Kernel 3: two-sided backtrack ----------------
__global__ __launch_bounds__(64, 1) void viterbi_bt(
    const float* __restrict__ ws_alpha, const float* __restrict__ ws_beta,
    const int* __restrict__ ws_lasttag, const int* __restrict__ mask,
    const float* __restrict__ scores, const float* __restrict__ trans,
    float* __restrict__ out_tags) {
  __shared__ float tP[NTAG * 65];  // tP[i*65+j] = trans[i][j]
  __shared__ int mk[256];
  __shared__ unsigned char tagb[256];
  const int lane = threadIdx.x;
  const int role = blockIdx.x >> 6;
  const int b = blockIdx.x & 63;

#pragma unroll
  for (int i = 0; i < NTAG; ++i) tP[i * 65 + lane] = trans[(size_t)i * NTAG + lane];
  const int tbase = role * 256;
  for (int t = lane; t < 256; t += 64) mk[t] = mask[b * TT + tbase + t];
  __syncthreads();

  int jcur = ws_lasttag[b];

  if (role == 0) {
    // prefix: tag_255 = jstar; s = 254..0 via alpha_s
    const float* wsA = ws_alpha + (size_t)b * 256 * NTAG;
    if (lane == 0) tagb[255] = (unsigned char)jcur;

    float a0 = wsA[(size_t)254 * NTAG + lane];
    float a1 = wsA[(size_t)253 * NTAG + lane];
    float a2 = wsA[(size_t)252 * NTAG + lane];
    float a3 = wsA[(size_t)251 * NTAG + lane];

    for (int s = 254; s >= 0; --s) {
      const float ac = a0;  // alpha_s
      a0 = a1; a1 = a2; a2 = a3;
      const int sp = (s >= 4) ? (s - 4) : 0;
      a3 = wsA[(size_t)sp * NTAG + lane];
      if (mk[s + 1]) {
        const float c = ac + tP[lane * 65 + jcur];
        const float cmx = dpp_red_max(c);
        jcur = (int)__builtin_ctzll(__ballot(c == cmx));
      }
      if (lane == 0) tagb[s] = (unsigned char)jcur;
    }
  } else {
    // suffix: t = 256..511; candidates per lane k = lane
    const float* wsB = ws_beta + (size_t)b * 256 * NTAG;
    const float* scb = scores + (size_t)b * TT * NTAG;
    float r0 = wsB[(size_t)0 * NTAG + lane], r1 = wsB[(size_t)1 * NTAG + lane];
    float r2 = wsB[(size_t)2 * NTAG + lane], r3 = wsB[(size_t)3 * NTAG + lane];
    float s0 = scb[(size_t)256 * NTAG + lane], s1 = scb[(size_t)257 * NTAG + lane];
    float s2 = scb[(size_t)258 * NTAG + lane], s3 = scb[(size_t)259 * NTAG + lane];

    for (int t = 256; t < TT; ++t) {
      const float bv = r0, sv = s0;
      const int tb = (t + 4 < TT) ? (t + 4) : (TT - 1);
      r0 = r1; r1 = r2; r2 = r3;
      r3 = wsB[(size_t)(tb - 256) * NTAG + lane];
      s0 = s1; s1 = s2; s2 = s3;
      s3 = scb[(size_t)tb * NTAG + lane];
      if (mk[t - 256]) {
        const float c = tP[jcur * 65 + lane] + sv + bv;
        const float cmx = dpp_red_max(c);
        jcur = (int)__builtin_ctzll(__ballot(c == cmx));
      }
      if (lane == 0) tagb[t - 256] = (unsigned char)jcur;
    }
  }
  __syncthreads();
  for (int t = lane; t < 256; t += 64)
    out_tags[b * TT + tbase + t] = (float)(mk[t] ? (int)tagb[t] : 0);
}

// ---------------- Kernel 4: loss = mean(log_z - gold) ----------------
__global__ __launch_bounds__(64, 1) void loss_mean(const float* __restrict__ ws_loss,
                                                   float* __restrict__ out) {
  const float v = ws_loss[threadIdx.x];
  const float s = dpp_red_sum(v);
  if (threadIdx.x == 0) out[0] = s * (1.0f / 64.0f);
}

extern "C" void kernel_launch(void* const* d_in, const int* in_sizes, int n_in,
                              void* d_out, int out_size, void* d_ws, size_t ws_size,
                              hipStream_t stream) {
  const float* X = (const float*)d_in[0];
  const int* mask = (const int*)d_in[1];
  const int* labels = (const int*)d_in[2];
  const float* W = (const float*)d_in[3];
  const float* bias = (const float*)d_in[4];
  const float* trans = (const float*)d_in[5];
  const float* startv = (const float*)d_in[6];
  const float* endv = (const float*)d_in[7];

  float* out = (float*)d_out;
  float* scores = out;
  float* out_tags = out + TAGS_OFF;
  float* out_loss = out + LOSS_OFF;

  unsigned short* wf_hi = (unsigned short*)d_ws;            // 65536 bf16
  unsigned short* wf_lo = wf_hi + 65536;                    // 65536 bf16
  float* ws_alpha = (float*)(wf_lo + 65536);                // 64*256*64 fp32
  float* ws_beta = ws_alpha + (size_t)BB * 256 * NTAG;      // 64*256*64 fp32
  float* zAcut = ws_beta + (size_t)BB * 256 * NTAG;         // 64*64
  float* bScut = zAcut + BB * NTAG;                         // 64*64
  float* bVcut = bScut + BB * NTAG;                         // 64*64
  float* Ca = bVcut + BB * NTAG;                            // 64
  float* Cb = Ca + BB;                                      // 64
  int* ws_lasttag = (int*)(Cb + BB);                        // 64
  float* ws_loss = (float*)(ws_lasttag + BB);               // 64

  prep_w<<<32, 256, 0, stream>>>(W, wf_hi, wf_lo);
  gemm_scores<<<2048, 256, 0, stream>>>(X, mask, wf_hi, wf_lo, bias, scores);
  crf_forward<<<256, 256, 0, stream>>>(scores, mask, trans, startv, endv,
                                       ws_alpha, ws_beta, zAcut, bScut, bVcut,
                                       Ca, Cb);
  crf_combine<<<64, 64, 0, stream>>>(scores, mask, labels, trans, startv, endv,
                                     ws_alpha, bVcut, zAcut, bScut, Ca, Cb,
                                     ws_lasttag, ws_loss);
  viterbi_bt<<<128, 64, 0, stream>>>(ws_alpha, ws_beta, ws_lasttag, mask,
                                     scores, trans, out_tags);
  loss_mean<<<1, 64, 0, stream>>>(ws_loss, out_loss);
}

// Round 11
// 374.046 us; speedup vs baseline: 1.0378x; 1.0378x over previous
//
#include <hip/hip_runtime.h>
#include <cstdint>
#include <cstddef>

#define BB 64
#define TT 512
#define DD 1024
#define NTAG 64
#define CUT 255  // prefix handles t<=CUT, suffix t>CUT; wsA/wsB each 256 slots
#define SCORES_ELEMS (BB * TT * NTAG)      // 2097152
#define TAGS_OFF SCORES_ELEMS              // 2097152
#define LOSS_OFF (SCORES_ELEMS + BB * TT)  // 2130920

typedef __attribute__((ext_vector_type(8))) short short8;
typedef __attribute__((ext_vector_type(4))) float floatx4;
typedef __attribute__((ext_vector_type(16))) float f32x16;

__device__ __forceinline__ unsigned short f2bf_rne(float x) {
  const unsigned int u = __float_as_uint(x);
  const unsigned int r = u + 0x7FFFu + ((u >> 16) & 1u);
  return (unsigned short)(r >> 16);
}
__device__ __forceinline__ float bf2f(unsigned short h) {
  return __uint_as_float(((unsigned int)h) << 16);
}

// Raw barrier: LDS-ordering only (no vmcnt drain; alpha/beta stores stay
// in flight across steps, nothing ever waits on them).
__device__ __forceinline__ void block_sync_lds() {
  asm volatile("s_waitcnt lgkmcnt(0)\n\ts_barrier" ::: "memory");
}

// quad_perm DPP: exchange with lane^1 / lane^2 (cross-chunk reduce partners)
__device__ __forceinline__ float quad_xor1(float v) {
  int x = __builtin_amdgcn_update_dpp(__float_as_int(v), __float_as_int(v), 0xB1, 0xf, 0xf, false);
  return __int_as_float(x);
}
__device__ __forceinline__ float quad_xor2(float v) {
  int x = __builtin_amdgcn_update_dpp(__float_as_int(v), __float_as_int(v), 0x4E, 0xf, 0xf, false);
  return __int_as_float(x);
}

// ---------------- DPP wave64 reductions ----------------
__device__ __forceinline__ float dpp_red_max(float v) {
  int x;
  x = __builtin_amdgcn_update_dpp(__float_as_int(v), __float_as_int(v), 0x111, 0xf, 0xf, false);
  v = fmaxf(v, __int_as_float(x));
  x = __builtin_amdgcn_update_dpp(__float_as_int(v), __float_as_int(v), 0x112, 0xf, 0xf, false);
  v = fmaxf(v, __int_as_float(x));
  x = __builtin_amdgcn_update_dpp(__float_as_int(v), __float_as_int(v), 0x114, 0xf, 0xf, false);
  v = fmaxf(v, __int_as_float(x));
  x = __builtin_amdgcn_update_dpp(__float_as_int(v), __float_as_int(v), 0x118, 0xf, 0xf, false);
  v = fmaxf(v, __int_as_float(x));
  x = __builtin_amdgcn_update_dpp(__float_as_int(v), __float_as_int(v), 0x142, 0xa, 0xf, false);
  v = fmaxf(v, __int_as_float(x));
  x = __builtin_amdgcn_update_dpp(__float_as_int(v), __float_as_int(v), 0x143, 0xc, 0xf, false);
  v = fmaxf(v, __int_as_float(x));
  return __int_as_float(__builtin_amdgcn_readlane(__float_as_int(v), 63));
}

__device__ __forceinline__ float dpp_red_sum(float v) {
  int x;
  x = __builtin_amdgcn_update_dpp(__float_as_int(v), __float_as_int(v), 0x111, 0xf, 0xf, false);
  v = v + __int_as_float(x);
  x = __builtin_amdgcn_update_dpp(__float_as_int(v), __float_as_int(v), 0x112, 0xf, 0xf, false);
  v = v + __int_as_float(x);
  x = __builtin_amdgcn_update_dpp(__float_as_int(v), __float_as_int(v), 0x114, 0xf, 0xf, false);
  v = v + __int_as_float(x);
  x = __builtin_amdgcn_update_dpp(__float_as_int(v), __float_as_int(v), 0x118, 0xf, 0xf, false);
  v = v + __int_as_float(x);
  x = __builtin_amdgcn_update_dpp(__float_as_int(v), __float_as_int(v), 0x142, 0xa, 0xf, false);
  v = v + __int_as_float(x);
  x = __builtin_amdgcn_update_dpp(__float_as_int(v), __float_as_int(v), 0x143, 0xc, 0xf, false);
  v = v + __int_as_float(x);
  return __int_as_float(__builtin_amdgcn_readlane(__float_as_int(v), 63));
}

// ---------------- Kernel 0: W -> bf16 hi/lo fragments (B-operand order) ----
__global__ __launch_bounds__(256) void prep_w(
    const float* __restrict__ W, unsigned short* __restrict__ wf_hi,
    unsigned short* __restrict__ wf_lo) {
  const int f = blockIdx.x * 256 + threadIdx.x;  // 0..8191
  const int kk = f >> 8;
  const int nt = (f >> 6) & 3;
  const int l = f & 63;
  const int n = nt * 16 + (l & 15);
  const int k0 = kk * 32 + ((l >> 4) << 3);
  short8 hv, lv;
#pragma unroll
  for (int j = 0; j < 8; ++j) {
    const float x = W[(size_t)(k0 + j) * NTAG + n];
    const unsigned short h = f2bf_rne(x);
    hv[j] = (short)h;
    lv[j] = (short)f2bf_rne(x - bf2f(h));
  }
  *reinterpret_cast<short8*>(wf_hi + (size_t)f * 8) = hv;
  *reinterpret_cast<short8*>(wf_lo + (size_t)f * 8) = lv;
}

// ---------------- Kernel 1: scores = (X @ W + b) * mask  (MFMA) ----------
// v8: 32-ROW TILES (1024 blocks). B-fragment L2 traffic was the gemm floor:
// 16-row tiles streamed 512KB x 2048 blocks = 1GB from L2 (~30us floor).
// Each wave now computes TWO 16-row A-fragments against the SAME B-frags:
// B traffic halves, MFMA per B-load doubles. Barrier-free split-K + A/B
// register double-buffer kept (R7/R9 validated).
__global__ __launch_bounds__(256, 2) void gemm_scores(
    const float* __restrict__ X, const int* __restrict__ mask,
    const unsigned short* __restrict__ wf_hi,
    const unsigned short* __restrict__ wf_lo,
    const float* __restrict__ bias, float* __restrict__ scores) {
  __shared__ float red[3 * 64 * 33];  // [wave-1][lane][32 acc vals], pad 33
  const int tid = threadIdx.x;
  const int lane = tid & 63;
  const int wv = tid >> 6;           // K-quarter id
  const int row0 = blockIdx.x * 32;  // output row tile (32 rows)
  const int arow = row0 + (lane & 15);
  const int aq = (lane >> 4) << 3;   // k sub-offset 0,8,16,24
  const float* Ap0 = X + (size_t)arow * DD + wv * 256 + aq;
  const float* Ap1 = Ap0 + (size_t)16 * DD;

  floatx4 acc[2][4];
#pragma unroll
  for (int f = 0; f < 2; ++f)
#pragma unroll
    for (int nt = 0; nt < 4; ++nt) acc[f][nt] = (floatx4)(0.f);

  // prefetch A chunk 0 (both row-fragments)
  float4 a00 = *reinterpret_cast<const float4*>(Ap0);
  float4 a01 = *reinterpret_cast<const float4*>(Ap0 + 4);
  float4 a10 = *reinterpret_cast<const float4*>(Ap1);
  float4 a11 = *reinterpret_cast<const float4*>(Ap1 + 4);

  // prefetch B chunk 0
  short8 cbh[4], cbl[4];
  {
    const size_t fbase0 = (size_t)(wv * 8) * 4 * 64 * 8;
#pragma unroll
    for (int nt = 0; nt < 4; ++nt) {
      const size_t off = fbase0 + ((size_t)nt * 64 + lane) * 8;
      cbh[nt] = *reinterpret_cast<const short8*>(wf_hi + off);
      cbl[nt] = *reinterpret_cast<const short8*>(wf_lo + off);
    }
  }

#pragma unroll
  for (int kk = 0; kk < 8; ++kk) {
    short8 ah0, al0, ah1, al1;
    {
      const float v0[8] = {a00.x, a00.y, a00.z, a00.w, a01.x, a01.y, a01.z, a01.w};
      const float v1[8] = {a10.x, a10.y, a10.z, a10.w, a11.x, a11.y, a11.z, a11.w};
#pragma unroll
      for (int e = 0; e < 8; ++e) {
        unsigned short h = f2bf_rne(v0[e]);
        ah0[e] = (short)h;
        al0[e] = (short)f2bf_rne(v0[e] - bf2f(h));
        h = f2bf_rne(v1[e]);
        ah1[e] = (short)h;
        al1[e] = (short)f2bf_rne(v1[e] - bf2f(h));
      }
    }
    // prefetch A + B for chunk kk+1 (hidden under this chunk's MFMAs)
    short8 nbh[4], nbl[4];
    if (kk < 7) {
      a00 = *reinterpret_cast<const float4*>(Ap0 + (kk + 1) * 32);
      a01 = *reinterpret_cast<const float4*>(Ap0 + (kk + 1) * 32 + 4);
      a10 = *reinterpret_cast<const float4*>(Ap1 + (kk + 1) * 32);
      a11 = *reinterpret_cast<const float4*>(Ap1 + (kk + 1) * 32 + 4);
      const size_t fbaseN = (size_t)(wv * 8 + kk + 1) * 4 * 64 * 8;
#pragma unroll
      for (int nt = 0; nt < 4; ++nt) {
        const size_t off = fbaseN + ((size_t)nt * 64 + lane) * 8;
        nbh[nt] = *reinterpret_cast<const short8*>(wf_hi + off);
        nbl[nt] = *reinterpret_cast<const short8*>(wf_lo + off);
      }
    }
#pragma unroll
    for (int nt = 0; nt < 4; ++nt) {
      acc[0][nt] = __builtin_amdgcn_mfma_f32_16x16x32_bf16(ah0, cbh[nt], acc[0][nt], 0, 0, 0);
      acc[0][nt] = __builtin_amdgcn_mfma_f32_16x16x32_bf16(ah0, cbl[nt], acc[0][nt], 0, 0, 0);
      acc[0][nt] = __builtin_amdgcn_mfma_f32_16x16x32_bf16(al0, cbh[nt], acc[0][nt], 0, 0, 0);
      acc[1][nt] = __builtin_amdgcn_mfma_f32_16x16x32_bf16(ah1, cbh[nt], acc[1][nt], 0, 0, 0);
      acc[1][nt] = __builtin_amdgcn_mfma_f32_16x16x32_bf16(ah1, cbl[nt], acc[1][nt], 0, 0, 0);
      acc[1][nt] = __builtin_amdgcn_mfma_f32_16x16x32_bf16(al1, cbh[nt], acc[1][nt], 0, 0, 0);
    }
    if (kk < 7) {
#pragma unroll
      for (int nt = 0; nt < 4; ++nt) { cbh[nt] = nbh[nt]; cbl[nt] = nbl[nt]; }
    }
  }

  if (wv > 0) {
    float* dst = &red[((wv - 1) * 64 + lane) * 33];
#pragma unroll
    for (int f = 0; f < 2; ++f)
#pragma unroll
      for (int nt = 0; nt < 4; ++nt)
#pragma unroll
        for (int r = 0; r < 4; ++r) dst[f * 16 + nt * 4 + r] = acc[f][nt][r];
  }
  __syncthreads();
  if (wv == 0) {
#pragma unroll
    for (int w = 0; w < 3; ++w) {
      const float* srcp = &red[(w * 64 + lane) * 33];
#pragma unroll
      for (int f = 0; f < 2; ++f)
#pragma unroll
        for (int nt = 0; nt < 4; ++nt)
#pragma unroll
          for (int r = 0; r < 4; ++r) acc[f][nt][r] += srcp[f * 16 + nt * 4 + r];
    }
    const int colb = lane & 15;
    const int quad = lane >> 4;
#pragma unroll
    for (int f = 0; f < 2; ++f) {
#pragma unroll
      for (int r = 0; r < 4; ++r) {
        const int row = row0 + f * 16 + quad * 4 + r;
        const float mf = (float)mask[row];
#pragma unroll
        for (int nt = 0; nt < 4; ++nt) {
          const int col = nt * 16 + colb;
          scores[(size_t)row * 64 + col] = (acc[f][nt][r] + bias[col]) * mf;
        }
      }
    }
  }
}

// ---------------- Kernel 2: forward+backward passes (4-wave cooperative) --
// Round-9 exact version (83us, best). Round-10's LDS-preload REGRESSED
// (92us): in-loop global loads were free; preload added LDS critical-path
// traffic. ~785 cyc/step is this structure's floor (barrier + LDS
// round-trip + dependent VALU). Roles:
//   0: fwd Viterbi  t=1..255   1: fwd sum  2: bwd Viterbi  3: bwd sum
__global__ __launch_bounds__(256, 1) void crf_forward(
    const float* __restrict__ scores, const int* __restrict__ mask,
    const float* __restrict__ trans, const float* __restrict__ startv,
    const float* __restrict__ endv, float* __restrict__ ws_alpha,
    float* __restrict__ ws_beta, float* __restrict__ zAcut,
    float* __restrict__ bScut, float* __restrict__ bVcut,
    float* __restrict__ Ca, float* __restrict__ Cb) {
  __shared__ float zbuf[2][NTAG];  // broadcast buffer
  __shared__ float part[4];        // cross-wave partials
  const int tid = threadIdx.x;
  const int wv = tid >> 6;     // wave id = output block
  const int lane = tid & 63;
  const int q = lane & 3;      // source chunk id (k in [16q,16q+16))
  const int jl = lane >> 2;    // 0..15
  const int j = wv * 16 + jl;  // owned output tag
  const int role = blockIdx.x >> 6;
  const int b = blockIdx.x & 63;
  const float* sc = scores + (size_t)b * TT * NTAG;
  const int* maskb = mask + b * TT;

  if (role == 0) {
    // ---- forward Viterbi (max-plus), t = 1..CUT ----
    f32x16 tc;  // tc[i2] = trans[16q+i2][j]  (column chunk)
#pragma unroll
    for (int i2 = 0; i2 < 16; ++i2)
      tc[i2] = trans[(size_t)(16 * q + i2) * NTAG + j];

    float aj = startv[j] + sc[j];  // alpha_0[j]
    if (q == 0) zbuf[0][j] = aj;
    float* wsA = ws_alpha + (size_t)b * 256 * NTAG;

    float e0 = sc[1 * NTAG + j], e1 = sc[2 * NTAG + j];
    float e2 = sc[3 * NTAG + j], e3 = sc[4 * NTAG + j];
    int k0 = maskb[1], k1 = maskb[2], k2 = maskb[3], k3 = maskb[4];
    __syncthreads();

    int cur = 0;
    for (int t = 1; t <= CUT; ++t) {
      if (q == 0) wsA[(size_t)(t - 1) * NTAG + j] = aj;  // alpha_{t-1}
      const float4 a0 = *reinterpret_cast<const float4*>(&zbuf[cur][q * 16 + 0]);
      const float4 a1 = *reinterpret_cast<const float4*>(&zbuf[cur][q * 16 + 4]);
      const float4 a2 = *reinterpret_cast<const float4*>(&zbuf[cur][q * 16 + 8]);
      const float4 a3 = *reinterpret_cast<const float4*>(&zbuf[cur][q * 16 + 12]);
      const float emit = e0;
      const int m = k0;
      const int tp = (t + 4 <= CUT) ? (t + 4) : CUT;
      e0 = e1; e1 = e2; e2 = e3;
      e3 = sc[(size_t)tp * NTAG + j];
      k0 = k1; k1 = k2; k2 = k3;
      k3 = maskb[tp];

      const float c0 = a0.x + tc[0],  c1 = a0.y + tc[1];
      const float c2 = a0.z + tc[2],  c3 = a0.w + tc[3];
      const float c4 = a1.x + tc[4],  c5 = a1.y + tc[5];
      const float c6 = a1.z + tc[6],  c7 = a1.w + tc[7];
      const float c8 = a2.x + tc[8],  c9 = a2.y + tc[9];
      const float cA = a2.z + tc[10], cB = a2.w + tc[11];
      const float cC = a3.x + tc[12], cD = a3.y + tc[13];
      const float cE = a3.z + tc[14], cF = a3.w + tc[15];
      const float h0 = fmaxf(fmaxf(c0, c1), fmaxf(c2, c3));
      const float h1 = fmaxf(fmaxf(c4, c5), fmaxf(c6, c7));
      const float h2 = fmaxf(fmaxf(c8, c9), fmaxf(cA, cB));
      const float h3 = fmaxf(fmaxf(cC, cD), fmaxf(cE, cF));
      float pm = fmaxf(fmaxf(h0, h1), fmaxf(h2, h3));
      pm = fmaxf(pm, quad_xor1(pm));
      pm = fmaxf(pm, quad_xor2(pm));

      aj = m ? (pm + emit) : aj;
      const int nxt = cur ^ 1;
      if (q == 0) zbuf[nxt][j] = aj;
      block_sync_lds();
      cur = nxt;
    }
    // export alpha_CUT into wsA slot 255 (combine reads it; bt prefix doesn't)
    if (q == 0) wsA[(size_t)255 * NTAG + j] = aj;
  } else if (role == 1) {
    // ---- forward sum-product (linear domain, periodic renorm), t=1..CUT --
    f32x16 ec;  // ec[i2] = exp(trans[16q+i2][j])
#pragma unroll
    for (int i2 = 0; i2 < 16; ++i2)
      ec[i2] = expf(trans[(size_t)(16 * q + i2) * NTAG + j]);

    const float a0v = startv[j] + sc[j];
    const float wm = dpp_red_max(a0v);
    if (lane == 0) part[wv] = wm;
    __syncthreads();
    const float M0 = fmaxf(fmaxf(part[0], part[1]), fmaxf(part[2], part[3]));
    float zj = expf(a0v - M0);
    float C = M0;
    if (q == 0) zbuf[0][j] = zj;

    float e0 = sc[1 * NTAG + j], e1 = sc[2 * NTAG + j];
    float e2 = sc[3 * NTAG + j], e3 = sc[4 * NTAG + j];
    int k0 = maskb[1], k1 = maskb[2], k2 = maskb[3], k3 = maskb[4];
    float pe = expf(e0);
    __syncthreads();

    int cur = 0;
    for (int t = 1; t <= CUT; ++t) {
      const float4 z0 = *reinterpret_cast<const float4*>(&zbuf[cur][q * 16 + 0]);
      const float4 z1 = *reinterpret_cast<const float4*>(&zbuf[cur][q * 16 + 4]);
      const float4 z2 = *reinterpret_cast<const float4*>(&zbuf[cur][q * 16 + 8]);
      const float4 z3 = *reinterpret_cast<const float4*>(&zbuf[cur][q * 16 + 12]);
      const float pec = pe;
      const int m = k0;
      const int tp = (t + 4 <= CUT) ? (t + 4) : CUT;
      e0 = e1; e1 = e2; e2 = e3;
      e3 = sc[(size_t)tp * NTAG + j];
      k0 = k1; k1 = k2; k2 = k3;
      k3 = maskb[tp];
      pe = expf(e0);

      float s0 = z0.x * ec[0], s1 = z0.y * ec[1];
      float s2 = z0.z * ec[2], s3 = z0.w * ec[3];
      s0 = fmaf(z1.x, ec[4], s0);  s1 = fmaf(z1.y, ec[5], s1);
      s2 = fmaf(z1.z, ec[6], s2);  s3 = fmaf(z1.w, ec[7], s3);
      s0 = fmaf(z2.x, ec[8], s0);  s1 = fmaf(z2.y, ec[9], s1);
      s2 = fmaf(z2.z, ec[10], s2); s3 = fmaf(z2.w, ec[11], s3);
      s0 = fmaf(z3.x, ec[12], s0); s1 = fmaf(z3.y, ec[13], s1);
      s2 = fmaf(z3.z, ec[14], s2); s3 = fmaf(z3.w, ec[15], s3);
      float s = (s0 + s1) + (s2 + s3);
      s += quad_xor1(s);
      s += quad_xor2(s);

      zj = m ? (s * pec) : zj;

      if ((t & 7) == 0) {
        const float ws = dpp_red_sum(zj);  // = 4 * per-wave sum
        if (lane == 0) part[wv] = ws;
        block_sync_lds();
        const float S4 = (part[0] + part[1]) + (part[2] + part[3]);
        const float r = __builtin_amdgcn_rcpf(S4);
        zj *= 4.0f * r;
        C += logf(S4) - 1.3862943611198906f;
      }

      const int nxt = cur ^ 1;
      if (q == 0) zbuf[nxt][j] = zj;
      block_sync_lds();
      cur = nxt;
    }
    if (q == 0) zAcut[b * NTAG + j] = zj;
    if (tid == 0) Ca[b] = C;
  } else if (role == 2) {
    // ---- backward Viterbi (max-plus), t = 511..256 ----
    f32x16 tc;  // ROW chunk: tc[i2] = trans[j][16q+i2] (contiguous)
#pragma unroll
    for (int i2 = 0; i2 < 16; ++i2)
      tc[i2] = trans[(size_t)j * NTAG + 16 * q + i2];

    float bj = endv[j];  // betaV_511
    float* wsB = ws_beta + (size_t)b * 256 * NTAG;
    if (q == 0) {
      wsB[(size_t)255 * NTAG + j] = bj;                 // betaV_511
      zbuf[0][j] = bj + sc[(size_t)511 * NTAG + j];     // h_511
    }
    float e0 = sc[(size_t)510 * NTAG + j], e1 = sc[(size_t)509 * NTAG + j];
    float e2 = sc[(size_t)508 * NTAG + j], e3 = sc[(size_t)507 * NTAG + j];
    int k0 = maskb[511], k1 = maskb[510], k2 = maskb[509], k3 = maskb[508];
    __syncthreads();

    int cur = 0;
    for (int t = 511; t >= 257; --t) {
      const float4 a0 = *reinterpret_cast<const float4*>(&zbuf[cur][q * 16 + 0]);
      const float4 a1 = *reinterpret_cast<const float4*>(&zbuf[cur][q * 16 + 4]);
      const float4 a2 = *reinterpret_cast<const float4*>(&zbuf[cur][q * 16 + 8]);
      const float4 a3 = *reinterpret_cast<const float4*>(&zbuf[cur][q * 16 + 12]);
      const float emit = e0;  // e_{t-1}
      const int m = k0;       // m_t
      const int tpe = (t - 5 >= 0) ? (t - 5) : 0;
      const int tpk = (t - 4 >= 256) ? (t - 4) : 256;
      e0 = e1; e1 = e2; e2 = e3;
      e3 = sc[(size_t)tpe * NTAG + j];
      k0 = k1; k1 = k2; k2 = k3;
      k3 = maskb[tpk];

      const float c0 = a0.x + tc[0],  c1 = a0.y + tc[1];
      const float c2 = a0.z + tc[2],  c3 = a0.w + tc[3];
      const float c4 = a1.x + tc[4],  c5 = a1.y + tc[5];
      const float c6 = a1.z + tc[6],  c7 = a1.w + tc[7];
      const float c8 = a2.x + tc[8],  c9 = a2.y + tc[9];
      const float cA = a2.z + tc[10], cB = a2.w + tc[11];
      const float cC = a3.x + tc[12], cD = a3.y + tc[13];
      const float cE = a3.z + tc[14], cF = a3.w + tc[15];
      const float h0 = fmaxf(fmaxf(c0, c1), fmaxf(c2, c3));
      const float h1 = fmaxf(fmaxf(c4, c5), fmaxf(c6, c7));
      const float h2 = fmaxf(fmaxf(c8, c9), fmaxf(cA, cB));
      const float h3 = fmaxf(fmaxf(cC, cD), fmaxf(cE, cF));
      float pm = fmaxf(fmaxf(h0, h1), fmaxf(h2, h3));
      pm = fmaxf(pm, quad_xor1(pm));
      pm = fmaxf(pm, quad_xor2(pm));

      bj = m ? pm : bj;  // betaV_{t-1}
      const int nxt = cur ^ 1;
      if (q == 0) {
        wsB[(size_t)(t - 1 - 256) * NTAG + j] = bj;  // betaV_{t-1}, idx 254..0
        zbuf[nxt][j] = bj + emit;                     // h_{t-1}
      }
      block_sync_lds();
      cur = nxt;
    }
    // epilogue t=256 -> betaV_255 (k0 = m_256; h_256 in zbuf[cur])
    {
      const float4 a0 = *reinterpret_cast<const float4*>(&zbuf[cur][q * 16 + 0]);
      const float4 a1 = *reinterpret_cast<const float4*>(&zbuf[cur][q * 16 + 4]);
      const float4 a2 = *reinterpret_cast<const float4*>(&zbuf[cur][q * 16 + 8]);
      const float4 a3 = *reinterpret_cast<const float4*>(&zbuf[cur][q * 16 + 12]);
      const float c0 = a0.x + tc[0],  c1 = a0.y + tc[1];
      const float c2 = a0.z + tc[2],  c3 = a0.w + tc[3];
      const float c4 = a1.x + tc[4],  c5 = a1.y + tc[5];
      const float c6 = a1.z + tc[6],  c7 = a1.w + tc[7];
      const float c8 = a2.x + tc[8],  c9 = a2.y + tc[9];
      const float cA = a2.z + tc[10], cB = a2.w + tc[11];
      const float cC = a3.x + tc[12], cD = a3.y + tc[13];
      const float cE = a3.z + tc[14], cF = a3.w + tc[15];
      const float h0 = fmaxf(fmaxf(c0, c1), fmaxf(c2, c3));
      const float h1 = fmaxf(fmaxf(c4, c5), fmaxf(c6, c7));
      const float h2 = fmaxf(fmaxf(c8, c9), fmaxf(cA, cB));
      const float h3 = fmaxf(fmaxf(cC, cD), fmaxf(cE, cF));
      float pm = fmaxf(fmaxf(h0, h1), fmaxf(h2, h3));
      pm = fmaxf(pm, quad_xor1(pm));
      pm = fmaxf(pm, quad_xor2(pm));
      bj = k0 ? pm : bj;  // betaV_255
      if (q == 0) bVcut[b * NTAG + j] = bj;
    }
  } else {
    // ---- backward sum-product, t = 511..256 ----
    f32x16 ec;  // ROW chunk: ec[i2] = exp(trans[j][16q+i2])
#pragma unroll
    for (int i2 = 0; i2 < 16; ++i2)
      ec[i2] = expf(trans[(size_t)j * NTAG + 16 * q + i2]);

    float bj = expf(endv[j]);  // bLin_511
    float C = 0.f;
    if (q == 0) zbuf[0][j] = bj * expf(sc[(size_t)511 * NTAG + j]);  // g_511
    float e0 = sc[(size_t)510 * NTAG + j], e1 = sc[(size_t)509 * NTAG + j];
    float e2 = sc[(size_t)508 * NTAG + j], e3 = sc[(size_t)507 * NTAG + j];
    int k0 = maskb[511], k1 = maskb[510], k2 = maskb[509], k3 = maskb[508];
    float pe = expf(e0);  // exp(e_{t-1}) for t=511
    __syncthreads();

    int cur = 0;
    for (int t = 511; t >= 257; --t) {
      const float4 z0 = *reinterpret_cast<const float4*>(&zbuf[cur][q * 16 + 0]);
      const float4 z1 = *reinterpret_cast<const float4*>(&zbuf[cur][q * 16 + 4]);
      const float4 z2 = *reinterpret_cast<const float4*>(&zbuf[cur][q * 16 + 8]);
      const float4 z3 = *reinterpret_cast<const float4*>(&zbuf[cur][q * 16 + 12]);
      const float pec = pe;  // exp(e_{t-1})
      const int m = k0;      // m_t
      const int tpe = (t - 5 >= 0) ? (t - 5) : 0;
      const int tpk = (t - 4 >= 256) ? (t - 4) : 256;
      e0 = e1; e1 = e2; e2 = e3;
      e3 = sc[(size_t)tpe * NTAG + j];
      k0 = k1; k1 = k2; k2 = k3;
      k3 = maskb[tpk];
      pe = expf(e0);

      float s0 = z0.x * ec[0], s1 = z0.y * ec[1];
      float s2 = z0.z * ec[2], s3 = z0.w * ec[3];
      s0 = fmaf(z1.x, ec[4], s0);  s1 = fmaf(z1.y, ec[5], s1);
      s2 = fmaf(z1.z, ec[6], s2);  s3 = fmaf(z1.w, ec[7], s3);
      s0 = fmaf(z2.x, ec[8], s0);  s1 = fmaf(z2.y, ec[9], s1);
      s2 = fmaf(z2.z, ec[10], s2); s3 = fmaf(z2.w, ec[11], s3);
      s0 = fmaf(z3.x, ec[12], s0); s1 = fmaf(z3.y, ec[13], s1);
      s2 = fmaf(z3.z, ec[14], s2); s3 = fmaf(z3.w, ec[15], s3);
      float s = (s0 + s1) + (s2 + s3);
      s += quad_xor1(s);
      s += quad_xor2(s);

      bj = m ? s : bj;  // bLin_{t-1}

      if ((t & 7) == 0) {
        const float ws = dpp_red_sum(bj);
        if (lane == 0) part[wv] = ws;
        block_sync_lds();
        const float S4 = (part[0] + part[1]) + (part[2] + part[3]);
        const float r = __builtin_amdgcn_rcpf(S4);
        bj *= 4.0f * r;
        C += logf(S4) - 1.3862943611198906f;
      }

      const int nxt = cur ^ 1;
      if (q == 0) zbuf[nxt][j] = bj * pec;  // g_{t-1}
      block_sync_lds();
      cur = nxt;
    }
    // epilogue t=256 -> bLin_255 (k0 = m_256)
    {
      const float4 z0 = *reinterpret_cast<const float4*>(&zbuf[cur][q * 16 + 0]);
      const float4 z1 = *reinterpret_cast<const float4*>(&zbuf[cur][q * 16 + 4]);
      const float4 z2 = *reinterpret_cast<const float4*>(&zbuf[cur][q * 16 + 8]);
      const float4 z3 = *reinterpret_cast<const float4*>(&zbuf[cur][q * 16 + 12]);
      float s0 = z0.x * ec[0], s1 = z0.y * ec[1];
      float s2 = z0.z * ec[2], s3 = z0.w * ec[3];
      s0 = fmaf(z1.x, ec[4], s0);  s1 = fmaf(z1.y, ec[5], s1);
      s2 = fmaf(z1.z, ec[6], s2);  s3 = fmaf(z1.w, ec[7], s3);
      s0 = fmaf(z2.x, ec[8], s0);  s1 = fmaf(z2.y, ec[9], s1);
      s2 = fmaf(z2.z, ec[10], s2); s3 = fmaf(z2.w, ec[11], s3);
      s0 = fmaf(z3.x, ec[12], s0); s1 = fmaf(z3.y, ec[13], s1);
      s2 = fmaf(z3.z, ec[14], s2); s3 = fmaf(z3.w, ec[15], s3);
      float s = (s0 + s1) + (s2 + s3);
      s += quad_xor1(s);
      s += quad_xor2(s);
      bj = k0 ? s : bj;  // bLin_255
      if (q == 0) bScut[b * NTAG + j] = bj;
      if (tid == 0) Cb[b] = C;
    }
  }
}

// ---------------- Kernel 2b: combine at the cut ----------------
__global__ __launch_bounds__(64, 1) void crf_combine(
    const float* __restrict__ scores, const int* __restrict__ mask,
    const int* __restrict__ labels, const float* __restrict__ trans,
    const float* __restrict__ startv, const float* __restrict__ endv,
    const float* __restrict__ ws_alpha, const float* __restrict__ bVcut,
    const float* __restrict__ zAcut, const float* __restrict__ bScut,
    const float* __restrict__ Ca, const float* __restrict__ Cb,
    int* __restrict__ ws_lasttag, float* __restrict__ ws_loss) {
  const int lane = threadIdx.x;
  const int b = blockIdx.x;
  const float* sc = scores + (size_t)b * TT * NTAG;
  const int* maskb = mask + b * TT;

  // Viterbi cut tag
  const float aV = ws_alpha[((size_t)b * 256 + 255) * NTAG + lane];
  const float fv = aV + bVcut[b * NTAG + lane];
  const float mx = dpp_red_max(fv);
  const int jstar = (int)__builtin_ctzll(__ballot(fv == mx));
  if (lane == 0) ws_lasttag[b] = jstar;

  // log Z
  const float S = dpp_red_sum(zAcut[b * NTAG + lane] * bScut[b * NTAG + lane]);
  const float log_z = logf(S) + Ca[b] + Cb[b];

  // gold score
  float g = 0.f, msumf = 0.f;
  for (int t = lane; t < TT; t += 64) {
    const int lab = labels[b * TT + t];
    const float mf = (float)maskb[t];
    msumf += mf;
    g += sc[(size_t)t * NTAG + lab] * mf;
    if (t >= 1) {
      const int labp = labels[b * TT + t - 1];
      g += trans[(size_t)labp * NTAG + lab] * mf;
    }
  }
  g = dpp_red_sum(g);
  const float msum = dpp_red_sum(msumf);
  const int last_idx = (int)msum - 1;
  g += startv[labels[b * TT]] + endv[labels[b * TT + last_idx]];
  if (lane == 0) ws_loss[b] = log_z - g;
}

// ---------------- Kernel 3: two-sided backtrack ----------------
__global__ __launch_bounds__(64, 1) void viterbi_bt(
    const float* __restrict__ ws_alpha, const float* __restrict__ ws_beta,
    const int* __restrict__ ws_lasttag, const int* __restrict__ mask,
    const float* __restrict__ scores, const float* __restrict__ trans,
    float* __restrict__ out_tags) {
  __shared__ float tP[NTAG * 65];  // tP[i*65+j] = trans[i][j]
  __shared__ int mk[256];
  __shared__ unsigned char tagb[256];
  const int lane = threadIdx.x;
  const int role = blockIdx.x >> 6;
  const int b = blockIdx.x & 63;

#pragma unroll
  for (int i = 0; i < NTAG; ++i) tP[i * 65 + lane] = trans[(size_t)i * NTAG + lane];
  const int tbase = role * 256;
  for (int t = lane; t < 256; t += 64) mk[t] = mask[b * TT + tbase + t];
  __syncthreads();

  int jcur = ws_lasttag[b];

  if (role == 0) {
    // prefix: tag_255 = jstar; s = 254..0 via alpha_s
    const float* wsA = ws_alpha + (size_t)b * 256 * NTAG;
    if (lane == 0) tagb[255] = (unsigned char)jcur;

    float a0 = wsA[(size_t)254 * NTAG + lane];
    float a1 = wsA[(size_t)253 * NTAG + lane];
    float a2 = wsA[(size_t)252 * NTAG + lane];
    float a3 = wsA[(size_t)251 * NTAG + lane];

    for (int s = 254; s >= 0; --s) {
      const float ac = a0;  // alpha_s
      a0 = a1; a1 = a2; a2 = a3;
      const int sp = (s >= 4) ? (s - 4) : 0;
      a3 = wsA[(size_t)sp * NTAG + lane];
      if (mk[s + 1]) {
        const float c = ac + tP[lane * 65 + jcur];
        const float cmx = dpp_red_max(c);
        jcur = (int)__builtin_ctzll(__ballot(c == cmx));
      }
      if (lane == 0) tagb[s] = (unsigned char)jcur;
    }
  } else {
    // suffix: t = 256..511; candidates per lane k = lane
    const float* wsB = ws_beta + (size_t)b * 256 * NTAG;
    const float* scb = scores + (size_t)b * TT * NTAG;
    float r0 = wsB[(size_t)0 * NTAG + lane], r1 = wsB[(size_t)1 * NTAG + lane];
    float r2 = wsB[(size_t)2 * NTAG + lane], r3 = wsB[(size_t)3 * NTAG + lane];
    float s0 = scb[(size_t)256 * NTAG + lane], s1 = scb[(size_t)257 * NTAG + lane];
    float s2 = scb[(size_t)258 * NTAG + lane], s3 = scb[(size_t)259 * NTAG + lane];

    for (int t = 256; t < TT; ++t) {
      const float bv = r0, sv = s0;
      const int tb = (t + 4 < TT) ? (t + 4) : (TT - 1);
      r0 = r1; r1 = r2; r2 = r3;
      r3 = wsB[(size_t)(tb - 256) * NTAG + lane];
      s0 = s1; s1 = s2; s2 = s3;
      s3 = scb[(size_t)tb * NTAG + lane];
      if (mk[t - 256]) {
        const float c = tP[jcur * 65 + lane] + sv + bv;
        const float cmx = dpp_red_max(c);
        jcur = (int)__builtin_ctzll(__ballot(c == cmx));
      }
      if (lane == 0) tagb[t - 256] = (unsigned char)jcur;
    }
  }
  __syncthreads();
  for (int t = lane; t < 256; t += 64)
    out_tags[b * TT + tbase + t] = (float)(mk[t] ? (int)tagb[t] : 0);
}

// ---------------- Kernel 4: loss = mean(log_z - gold) ----------------
__global__ __launch_bounds__(64, 1) void loss_mean(const float* __restrict__ ws_loss,
                                                   float* __restrict__ out) {
  const float v = ws_loss[threadIdx.x];
  const float s = dpp_red_sum(v);
  if (threadIdx.x == 0) out[0] = s * (1.0f / 64.0f);
}

extern "C" void kernel_launch(void* const* d_in, const int* in_sizes, int n_in,
                              void* d_out, int out_size, void* d_ws, size_t ws_size,
                              hipStream_t stream) {
  const float* X = (const float*)d_in[0];
  const int* mask = (const int*)d_in[1];
  const int* labels = (const int*)d_in[2];
  const float* W = (const float*)d_in[3];
  const float* bias = (const float*)d_in[4];
  const float* trans = (const float*)d_in[5];
  const float* startv = (const float*)d_in[6];
  const float* endv = (const float*)d_in[7];

  float* out = (float*)d_out;
  float* scores = out;
  float* out_tags = out + TAGS_OFF;
  float* out_loss = out + LOSS_OFF;

  unsigned short* wf_hi = (unsigned short*)d_ws;            // 65536 bf16
  unsigned short* wf_lo = wf_hi + 65536;                    // 65536 bf16
  float* ws_alpha = (float*)(wf_lo + 65536);                // 64*256*64 fp32
  float* ws_beta = ws_alpha + (size_t)BB * 256 * NTAG;      // 64*256*64 fp32
  float* zAcut = ws_beta + (size_t)BB * 256 * NTAG;         // 64*64
  float* bScut = zAcut + BB * NTAG;                         // 64*64
  float* bVcut = bScut + BB * NTAG;                         // 64*64
  float* Ca = bVcut + BB * NTAG;                            // 64
  float* Cb = Ca + BB;                                      // 64
  int* ws_lasttag = (int*)(Cb + BB);                        // 64
  float* ws_loss = (float*)(ws_lasttag + BB);               // 64

  prep_w<<<32, 256, 0, stream>>>(W, wf_hi, wf_lo);
  gemm_scores<<<1024, 256, 0, stream>>>(X, mask, wf_hi, wf_lo, bias, scores);
  crf_forward<<<256, 256, 0, stream>>>(scores, mask, trans, startv, endv,
                                       ws_alpha, ws_beta, zAcut, bScut, bVcut,
                                       Ca, Cb);
  crf_combine<<<64, 64, 0, stream>>>(scores, mask, labels, trans, startv, endv,
                                     ws_alpha, bVcut, zAcut, bScut, Ca, Cb,
                                     ws_lasttag, ws_loss);
  viterbi_bt<<<128, 64, 0, stream>>>(ws_alpha, ws_beta, ws_lasttag, mask,
                                     scores, trans, out_tags);
  loss_mean<<<1, 64, 0, stream>>>(ws_loss, out_loss);
}

// Round 12
// 363.366 us; speedup vs baseline: 1.0683x; 1.0294x over previous
//
#include <hip/hip_runtime.h>
#include <cstdint>
#include <cstddef>

#define BB 64
#define TT 512
#define DD 1024
#define NTAG 64
#define CUT 255  // prefix handles t<=CUT, suffix t>CUT; wsA/wsB each 256 slots
#define SCORES_ELEMS (BB * TT * NTAG)      // 2097152
#define TAGS_OFF SCORES_ELEMS              // 2097152
#define LOSS_OFF (SCORES_ELEMS + BB * TT)  // 2130920

typedef __attribute__((ext_vector_type(8))) short short8;
typedef __attribute__((ext_vector_type(4))) float floatx4;
typedef __attribute__((ext_vector_type(16))) float f32x16;

__device__ __forceinline__ unsigned short f2bf_rne(float x) {
  const unsigned int u = __float_as_uint(x);
  const unsigned int r = u + 0x7FFFu + ((u >> 16) & 1u);
  return (unsigned short)(r >> 16);
}
__device__ __forceinline__ float bf2f(unsigned short h) {
  return __uint_as_float(((unsigned int)h) << 16);
}

// Raw barrier: LDS-ordering only (no vmcnt drain; alpha/beta stores stay
// in flight across steps, nothing ever waits on them).
__device__ __forceinline__ void block_sync_lds() {
  asm volatile("s_waitcnt lgkmcnt(0)\n\ts_barrier" ::: "memory");
}

// quad_perm DPP: exchange with lane^1 / lane^2 (cross-chunk reduce partners)
__device__ __forceinline__ float quad_xor1(float v) {
  int x = __builtin_amdgcn_update_dpp(__float_as_int(v), __float_as_int(v), 0xB1, 0xf, 0xf, false);
  return __int_as_float(x);
}
__device__ __forceinline__ float quad_xor2(float v) {
  int x = __builtin_amdgcn_update_dpp(__float_as_int(v), __float_as_int(v), 0x4E, 0xf, 0xf, false);
  return __int_as_float(x);
}

// ---------------- DPP wave64 reductions ----------------
__device__ __forceinline__ float dpp_red_max(float v) {
  int x;
  x = __builtin_amdgcn_update_dpp(__float_as_int(v), __float_as_int(v), 0x111, 0xf, 0xf, false);
  v = fmaxf(v, __int_as_float(x));
  x = __builtin_amdgcn_update_dpp(__float_as_int(v), __float_as_int(v), 0x112, 0xf, 0xf, false);
  v = fmaxf(v, __int_as_float(x));
  x = __builtin_amdgcn_update_dpp(__float_as_int(v), __float_as_int(v), 0x114, 0xf, 0xf, false);
  v = fmaxf(v, __int_as_float(x));
  x = __builtin_amdgcn_update_dpp(__float_as_int(v), __float_as_int(v), 0x118, 0xf, 0xf, false);
  v = fmaxf(v, __int_as_float(x));
  x = __builtin_amdgcn_update_dpp(__float_as_int(v), __float_as_int(v), 0x142, 0xa, 0xf, false);
  v = fmaxf(v, __int_as_float(x));
  x = __builtin_amdgcn_update_dpp(__float_as_int(v), __float_as_int(v), 0x143, 0xc, 0xf, false);
  v = fmaxf(v, __int_as_float(x));
  return __int_as_float(__builtin_amdgcn_readlane(__float_as_int(v), 63));
}

__device__ __forceinline__ float dpp_red_sum(float v) {
  int x;
  x = __builtin_amdgcn_update_dpp(__float_as_int(v), __float_as_int(v), 0x111, 0xf, 0xf, false);
  v = v + __int_as_float(x);
  x = __builtin_amdgcn_update_dpp(__float_as_int(v), __float_as_int(v), 0x112, 0xf, 0xf, false);
  v = v + __int_as_float(x);
  x = __builtin_amdgcn_update_dpp(__float_as_int(v), __float_as_int(v), 0x114, 0xf, 0xf, false);
  v = v + __int_as_float(x);
  x = __builtin_amdgcn_update_dpp(__float_as_int(v), __float_as_int(v), 0x118, 0xf, 0xf, false);
  v = v + __int_as_float(x);
  x = __builtin_amdgcn_update_dpp(__float_as_int(v), __float_as_int(v), 0x142, 0xa, 0xf, false);
  v = v + __int_as_float(x);
  x = __builtin_amdgcn_update_dpp(__float_as_int(v), __float_as_int(v), 0x143, 0xc, 0xf, false);
  v = v + __int_as_float(x);
  return __int_as_float(__builtin_amdgcn_readlane(__float_as_int(v), 63));
}

// ---------------- Kernel 0: W -> bf16 hi/lo fragments (B-operand order) ----
__global__ __launch_bounds__(256) void prep_w(
    const float* __restrict__ W, unsigned short* __restrict__ wf_hi,
    unsigned short* __restrict__ wf_lo) {
  const int f = blockIdx.x * 256 + threadIdx.x;  // 0..8191
  const int kk = f >> 8;
  const int nt = (f >> 6) & 3;
  const int l = f & 63;
  const int n = nt * 16 + (l & 15);
  const int k0 = kk * 32 + ((l >> 4) << 3);
  short8 hv, lv;
#pragma unroll
  for (int j = 0; j < 8; ++j) {
    const float x = W[(size_t)(k0 + j) * NTAG + n];
    const unsigned short h = f2bf_rne(x);
    hv[j] = (short)h;
    lv[j] = (short)f2bf_rne(x - bf2f(h));
  }
  *reinterpret_cast<short8*>(wf_hi + (size_t)f * 8) = hv;
  *reinterpret_cast<short8*>(wf_lo + (size_t)f * 8) = lv;
}

// ---------------- Kernel 1: scores = (X @ W + b) * mask  (MFMA) ----------
// 32-row tiles + barrier-free split-K + A/B register double-buffer (R11).
// Also zeroes out_loss (bt's loss blocks atomicAdd into it; stream order
// guarantees gemm completes before bt starts).
__global__ __launch_bounds__(256, 2) void gemm_scores(
    const float* __restrict__ X, const int* __restrict__ mask,
    const unsigned short* __restrict__ wf_hi,
    const unsigned short* __restrict__ wf_lo,
    const float* __restrict__ bias, float* __restrict__ scores,
    float* __restrict__ out_loss) {
  __shared__ float red[3 * 64 * 33];  // [wave-1][lane][32 acc vals], pad 33
  const int tid = threadIdx.x;
  if (blockIdx.x == 0 && tid == 0) out_loss[0] = 0.f;
  const int lane = tid & 63;
  const int wv = tid >> 6;           // K-quarter id
  const int row0 = blockIdx.x * 32;  // output row tile (32 rows)
  const int arow = row0 + (lane & 15);
  const int aq = (lane >> 4) << 3;   // k sub-offset 0,8,16,24
  const float* Ap0 = X + (size_t)arow * DD + wv * 256 + aq;
  const float* Ap1 = Ap0 + (size_t)16 * DD;

  floatx4 acc[2][4];
#pragma unroll
  for (int f = 0; f < 2; ++f)
#pragma unroll
    for (int nt = 0; nt < 4; ++nt) acc[f][nt] = (floatx4)(0.f);

  // prefetch A chunk 0 (both row-fragments)
  float4 a00 = *reinterpret_cast<const float4*>(Ap0);
  float4 a01 = *reinterpret_cast<const float4*>(Ap0 + 4);
  float4 a10 = *reinterpret_cast<const float4*>(Ap1);
  float4 a11 = *reinterpret_cast<const float4*>(Ap1 + 4);

  // prefetch B chunk 0
  short8 cbh[4], cbl[4];
  {
    const size_t fbase0 = (size_t)(wv * 8) * 4 * 64 * 8;
#pragma unroll
    for (int nt = 0; nt < 4; ++nt) {
      const size_t off = fbase0 + ((size_t)nt * 64 + lane) * 8;
      cbh[nt] = *reinterpret_cast<const short8*>(wf_hi + off);
      cbl[nt] = *reinterpret_cast<const short8*>(wf_lo + off);
    }
  }

#pragma unroll
  for (int kk = 0; kk < 8; ++kk) {
    short8 ah0, al0, ah1, al1;
    {
      const float v0[8] = {a00.x, a00.y, a00.z, a00.w, a01.x, a01.y, a01.z, a01.w};
      const float v1[8] = {a10.x, a10.y, a10.z, a10.w, a11.x, a11.y, a11.z, a11.w};
#pragma unroll
      for (int e = 0; e < 8; ++e) {
        unsigned short h = f2bf_rne(v0[e]);
        ah0[e] = (short)h;
        al0[e] = (short)f2bf_rne(v0[e] - bf2f(h));
        h = f2bf_rne(v1[e]);
        ah1[e] = (short)h;
        al1[e] = (short)f2bf_rne(v1[e] - bf2f(h));
      }
    }
    // prefetch A + B for chunk kk+1 (hidden under this chunk's MFMAs)
    short8 nbh[4], nbl[4];
    if (kk < 7) {
      a00 = *reinterpret_cast<const float4*>(Ap0 + (kk + 1) * 32);
      a01 = *reinterpret_cast<const float4*>(Ap0 + (kk + 1) * 32 + 4);
      a10 = *reinterpret_cast<const float4*>(Ap1 + (kk + 1) * 32);
      a11 = *reinterpret_cast<const float4*>(Ap1 + (kk + 1) * 32 + 4);
      const size_t fbaseN = (size_t)(wv * 8 + kk + 1) * 4 * 64 * 8;
#pragma unroll
      for (int nt = 0; nt < 4; ++nt) {
        const size_t off = fbaseN + ((size_t)nt * 64 + lane) * 8;
        nbh[nt] = *reinterpret_cast<const short8*>(wf_hi + off);
        nbl[nt] = *reinterpret_cast<const short8*>(wf_lo + off);
      }
    }
#pragma unroll
    for (int nt = 0; nt < 4; ++nt) {
      acc[0][nt] = __builtin_amdgcn_mfma_f32_16x16x32_bf16(ah0, cbh[nt], acc[0][nt], 0, 0, 0);
      acc[0][nt] = __builtin_amdgcn_mfma_f32_16x16x32_bf16(ah0, cbl[nt], acc[0][nt], 0, 0, 0);
      acc[0][nt] = __builtin_amdgcn_mfma_f32_16x16x32_bf16(al0, cbh[nt], acc[0][nt], 0, 0, 0);
      acc[1][nt] = __builtin_amdgcn_mfma_f32_16x16x32_bf16(ah1, cbh[nt], acc[1][nt], 0, 0, 0);
      acc[1][nt] = __builtin_amdgcn_mfma_f32_16x16x32_bf16(ah1, cbl[nt], acc[1][nt], 0, 0, 0);
      acc[1][nt] = __builtin_amdgcn_mfma_f32_16x16x32_bf16(al1, cbh[nt], acc[1][nt], 0, 0, 0);
    }
    if (kk < 7) {
#pragma unroll
      for (int nt = 0; nt < 4; ++nt) { cbh[nt] = nbh[nt]; cbl[nt] = nbl[nt]; }
    }
  }

  if (wv > 0) {
    float* dst = &red[((wv - 1) * 64 + lane) * 33];
#pragma unroll
    for (int f = 0; f < 2; ++f)
#pragma unroll
      for (int nt = 0; nt < 4; ++nt)
#pragma unroll
        for (int r = 0; r < 4; ++r) dst[f * 16 + nt * 4 + r] = acc[f][nt][r];
  }
  __syncthreads();
  if (wv == 0) {
#pragma unroll
    for (int w = 0; w < 3; ++w) {
      const float* srcp = &red[(w * 64 + lane) * 33];
#pragma unroll
      for (int f = 0; f < 2; ++f)
#pragma unroll
        for (int nt = 0; nt < 4; ++nt)
#pragma unroll
          for (int r = 0; r < 4; ++r) acc[f][nt][r] += srcp[f * 16 + nt * 4 + r];
    }
    const int colb = lane & 15;
    const int quad = lane >> 4;
#pragma unroll
    for (int f = 0; f < 2; ++f) {
#pragma unroll
      for (int r = 0; r < 4; ++r) {
        const int row = row0 + f * 16 + quad * 4 + r;
        const float mf = (float)mask[row];
#pragma unroll
        for (int nt = 0; nt < 4; ++nt) {
          const int col = nt * 16 + colb;
          scores[(size_t)row * 64 + col] = (acc[f][nt][r] + bias[col]) * mf;
        }
      }
    }
  }
}

// ---------------- Kernel 2: forward+backward passes (4-wave cooperative) --
// Round-9 known-best (83us). Roles: 0 fwdV t=1..255, 1 fwdS, 2 bwdV
// t=511..256, 3 bwdS. ~785 cyc/step = structure floor.
__global__ __launch_bounds__(256, 1) void crf_forward(
    const float* __restrict__ scores, const int* __restrict__ mask,
    const float* __restrict__ trans, const float* __restrict__ startv,
    const float* __restrict__ endv, float* __restrict__ ws_alpha,
    float* __restrict__ ws_beta, float* __restrict__ zAcut,
    float* __restrict__ bScut, float* __restrict__ bVcut,
    float* __restrict__ Ca, float* __restrict__ Cb) {
  __shared__ float zbuf[2][NTAG];  // broadcast buffer
  __shared__ float part[4];        // cross-wave partials
  const int tid = threadIdx.x;
  const int wv = tid >> 6;     // wave id = output block
  const int lane = tid & 63;
  const int q = lane & 3;      // source chunk id (k in [16q,16q+16))
  const int jl = lane >> 2;    // 0..15
  const int j = wv * 16 + jl;  // owned output tag
  const int role = blockIdx.x >> 6;
  const int b = blockIdx.x & 63;
  const float* sc = scores + (size_t)b * TT * NTAG;
  const int* maskb = mask + b * TT;

  if (role == 0) {
    // ---- forward Viterbi (max-plus), t = 1..CUT ----
    f32x16 tc;  // tc[i2] = trans[16q+i2][j]  (column chunk)
#pragma unroll
    for (int i2 = 0; i2 < 16; ++i2)
      tc[i2] = trans[(size_t)(16 * q + i2) * NTAG + j];

    float aj = startv[j] + sc[j];  // alpha_0[j]
    if (q == 0) zbuf[0][j] = aj;
    float* wsA = ws_alpha + (size_t)b * 256 * NTAG;

    float e0 = sc[1 * NTAG + j], e1 = sc[2 * NTAG + j];
    float e2 = sc[3 * NTAG + j], e3 = sc[4 * NTAG + j];
    int k0 = maskb[1], k1 = maskb[2], k2 = maskb[3], k3 = maskb[4];
    __syncthreads();

    int cur = 0;
    for (int t = 1; t <= CUT; ++t) {
      if (q == 0) wsA[(size_t)(t - 1) * NTAG + j] = aj;  // alpha_{t-1}
      const float4 a0 = *reinterpret_cast<const float4*>(&zbuf[cur][q * 16 + 0]);
      const float4 a1 = *reinterpret_cast<const float4*>(&zbuf[cur][q * 16 + 4]);
      const float4 a2 = *reinterpret_cast<const float4*>(&zbuf[cur][q * 16 + 8]);
      const float4 a3 = *reinterpret_cast<const float4*>(&zbuf[cur][q * 16 + 12]);
      const float emit = e0;
      const int m = k0;
      const int tp = (t + 4 <= CUT) ? (t + 4) : CUT;
      e0 = e1; e1 = e2; e2 = e3;
      e3 = sc[(size_t)tp * NTAG + j];
      k0 = k1; k1 = k2; k2 = k3;
      k3 = maskb[tp];

      const float c0 = a0.x + tc[0],  c1 = a0.y + tc[1];
      const float c2 = a0.z + tc[2],  c3 = a0.w + tc[3];
      const float c4 = a1.x + tc[4],  c5 = a1.y + tc[5];
      const float c6 = a1.z + tc[6],  c7 = a1.w + tc[7];
      const float c8 = a2.x + tc[8],  c9 = a2.y + tc[9];
      const float cA = a2.z + tc[10], cB = a2.w + tc[11];
      const float cC = a3.x + tc[12], cD = a3.y + tc[13];
      const float cE = a3.z + tc[14], cF = a3.w + tc[15];
      const float h0 = fmaxf(fmaxf(c0, c1), fmaxf(c2, c3));
      const float h1 = fmaxf(fmaxf(c4, c5), fmaxf(c6, c7));
      const float h2 = fmaxf(fmaxf(c8, c9), fmaxf(cA, cB));
      const float h3 = fmaxf(fmaxf(cC, cD), fmaxf(cE, cF));
      float pm = fmaxf(fmaxf(h0, h1), fmaxf(h2, h3));
      pm = fmaxf(pm, quad_xor1(pm));
      pm = fmaxf(pm, quad_xor2(pm));

      aj = m ? (pm + emit) : aj;
      const int nxt = cur ^ 1;
      if (q == 0) zbuf[nxt][j] = aj;
      block_sync_lds();
      cur = nxt;
    }
    // export alpha_CUT into wsA slot 255 (bt reads it for jstar)
    if (q == 0) wsA[(size_t)255 * NTAG + j] = aj;
  } else if (role == 1) {
    // ---- forward sum-product (linear domain, periodic renorm), t=1..CUT --
    f32x16 ec;  // ec[i2] = exp(trans[16q+i2][j])
#pragma unroll
    for (int i2 = 0; i2 < 16; ++i2)
      ec[i2] = expf(trans[(size_t)(16 * q + i2) * NTAG + j]);

    const float a0v = startv[j] + sc[j];
    const float wm = dpp_red_max(a0v);
    if (lane == 0) part[wv] = wm;
    __syncthreads();
    const float M0 = fmaxf(fmaxf(part[0], part[1]), fmaxf(part[2], part[3]));
    float zj = expf(a0v - M0);
    float C = M0;
    if (q == 0) zbuf[0][j] = zj;

    float e0 = sc[1 * NTAG + j], e1 = sc[2 * NTAG + j];
    float e2 = sc[3 * NTAG + j], e3 = sc[4 * NTAG + j];
    int k0 = maskb[1], k1 = maskb[2], k2 = maskb[3], k3 = maskb[4];
    float pe = expf(e0);
    __syncthreads();

    int cur = 0;
    for (int t = 1; t <= CUT; ++t) {
      const float4 z0 = *reinterpret_cast<const float4*>(&zbuf[cur][q * 16 + 0]);
      const float4 z1 = *reinterpret_cast<const float4*>(&zbuf[cur][q * 16 + 4]);
      const float4 z2 = *reinterpret_cast<const float4*>(&zbuf[cur][q * 16 + 8]);
      const float4 z3 = *reinterpret_cast<const float4*>(&zbuf[cur][q * 16 + 12]);
      const float pec = pe;
      const int m = k0;
      const int tp = (t + 4 <= CUT) ? (t + 4) : CUT;
      e0 = e1; e1 = e2; e2 = e3;
      e3 = sc[(size_t)tp * NTAG + j];
      k0 = k1; k1 = k2; k2 = k3;
      k3 = maskb[tp];
      pe = expf(e0);

      float s0 = z0.x * ec[0], s1 = z0.y * ec[1];
      float s2 = z0.z * ec[2], s3 = z0.w * ec[3];
      s0 = fmaf(z1.x, ec[4], s0);  s1 = fmaf(z1.y, ec[5], s1);
      s2 = fmaf(z1.z, ec[6], s2);  s3 = fmaf(z1.w, ec[7], s3);
      s0 = fmaf(z2.x, ec[8], s0);  s1 = fmaf(z2.y, ec[9], s1);
      s2 = fmaf(z2.z, ec[10], s2); s3 = fmaf(z2.w, ec[11], s3);
      s0 = fmaf(z3.x, ec[12], s0); s1 = fmaf(z3.y, ec[13], s1);
      s2 = fmaf(z3.z, ec[14], s2); s3 = fmaf(z3.w, ec[15], s3);
      float s = (s0 + s1) + (s2 + s3);
      s += quad_xor1(s);
      s += quad_xor2(s);

      zj = m ? (s * pec) : zj;

      if ((t & 7) == 0) {
        const float ws = dpp_red_sum(zj);  // = 4 * per-wave sum
        if (lane == 0) part[wv] = ws;
        block_sync_lds();
        const float S4 = (part[0] + part[1]) + (part[2] + part[3]);
        const float r = __builtin_amdgcn_rcpf(S4);
        zj *= 4.0f * r;
        C += logf(S4) - 1.3862943611198906f;
      }

      const int nxt = cur ^ 1;
      if (q == 0) zbuf[nxt][j] = zj;
      block_sync_lds();
      cur = nxt;
    }
    if (q == 0) zAcut[b * NTAG + j] = zj;
    if (tid == 0) Ca[b] = C;
  } else if (role == 2) {
    // ---- backward Viterbi (max-plus), t = 511..256 ----
    f32x16 tc;  // ROW chunk: tc[i2] = trans[j][16q+i2] (contiguous)
#pragma unroll
    for (int i2 = 0; i2 < 16; ++i2)
      tc[i2] = trans[(size_t)j * NTAG + 16 * q + i2];

    float bj = endv[j];  // betaV_511
    float* wsB = ws_beta + (size_t)b * 256 * NTAG;
    if (q == 0) {
      wsB[(size_t)255 * NTAG + j] = bj;                 // betaV_511
      zbuf[0][j] = bj + sc[(size_t)511 * NTAG + j];     // h_511
    }
    float e0 = sc[(size_t)510 * NTAG + j], e1 = sc[(size_t)509 * NTAG + j];
    float e2 = sc[(size_t)508 * NTAG + j], e3 = sc[(size_t)507 * NTAG + j];
    int k0 = maskb[511], k1 = maskb[510], k2 = maskb[509], k3 = maskb[508];
    __syncthreads();

    int cur = 0;
    for (int t = 511; t >= 257; --t) {
      const float4 a0 = *reinterpret_cast<const float4*>(&zbuf[cur][q * 16 + 0]);
      const float4 a1 = *reinterpret_cast<const float4*>(&zbuf[cur][q * 16 + 4]);
      const float4 a2 = *reinterpret_cast<const float4*>(&zbuf[cur][q * 16 + 8]);
      const float4 a3 = *reinterpret_cast<const float4*>(&zbuf[cur][q * 16 + 12]);
      const float emit = e0;  // e_{t-1}
      const int m = k0;       // m_t
      const int tpe = (t - 5 >= 0) ? (t - 5) : 0;
      const int tpk = (t - 4 >= 256) ? (t - 4) : 256;
      e0 = e1; e1 = e2; e2 = e3;
      e3 = sc[(size_t)tpe * NTAG + j];
      k0 = k1; k1 = k2; k2 = k3;
      k3 = maskb[tpk];

      const float c0 = a0.x + tc[0],  c1 = a0.y + tc[1];
      const float c2 = a0.z + tc[2],  c3 = a0.w + tc[3];
      const float c4 = a1.x + tc[4],  c5 = a1.y + tc[5];
      const float c6 = a1.z + tc[6],  c7 = a1.w + tc[7];
      const float c8 = a2.x + tc[8],  c9 = a2.y + tc[9];
      const float cA = a2.z + tc[10], cB = a2.w + tc[11];
      const float cC = a3.x + tc[12], cD = a3.y + tc[13];
      const float cE = a3.z + tc[14], cF = a3.w + tc[15];
      const float h0 = fmaxf(fmaxf(c0, c1), fmaxf(c2, c3));
      const float h1 = fmaxf(fmaxf(c4, c5), fmaxf(c6, c7));
      const float h2 = fmaxf(fmaxf(c8, c9), fmaxf(cA, cB));
      const float h3 = fmaxf(fmaxf(cC, cD), fmaxf(cE, cF));
      float pm = fmaxf(fmaxf(h0, h1), fmaxf(h2, h3));
      pm = fmaxf(pm, quad_xor1(pm));
      pm = fmaxf(pm, quad_xor2(pm));

      bj = m ? pm : bj;  // betaV_{t-1}
      const int nxt = cur ^ 1;
      if (q == 0) {
        wsB[(size_t)(t - 1 - 256) * NTAG + j] = bj;  // betaV_{t-1}, idx 254..0
        zbuf[nxt][j] = bj + emit;                     // h_{t-1}
      }
      block_sync_lds();
      cur = nxt;
    }
    // epilogue t=256 -> betaV_255 (k0 = m_256; h_256 in zbuf[cur])
    {
      const float4 a0 = *reinterpret_cast<const float4*>(&zbuf[cur][q * 16 + 0]);
      const float4 a1 = *reinterpret_cast<const float4*>(&zbuf[cur][q * 16 + 4]);
      const float4 a2 = *reinterpret_cast<const float4*>(&zbuf[cur][q * 16 + 8]);
      const float4 a3 = *reinterpret_cast<const float4*>(&zbuf[cur][q * 16 + 12]);
      const float c0 = a0.x + tc[0],  c1 = a0.y + tc[1];
      const float c2 = a0.z + tc[2],  c3 = a0.w + tc[3];
      const float c4 = a1.x + tc[4],  c5 = a1.y + tc[5];
      const float c6 = a1.z + tc[6],  c7 = a1.w + tc[7];
      const float c8 = a2.x + tc[8],  c9 = a2.y + tc[9];
      const float cA = a2.z + tc[10], cB = a2.w + tc[11];
      const float cC = a3.x + tc[12], cD = a3.y + tc[13];
      const float cE = a3.z + tc[14], cF = a3.w + tc[15];
      const float h0 = fmaxf(fmaxf(c0, c1), fmaxf(c2, c3));
      const float h1 = fmaxf(fmaxf(c4, c5), fmaxf(c6, c7));
      const float h2 = fmaxf(fmaxf(c8, c9), fmaxf(cA, cB));
      const float h3 = fmaxf(fmaxf(cC, cD), fmaxf(cE, cF));
      float pm = fmaxf(fmaxf(h0, h1), fmaxf(h2, h3));
      pm = fmaxf(pm, quad_xor1(pm));
      pm = fmaxf(pm, quad_xor2(pm));
      bj = k0 ? pm : bj;  // betaV_255
      if (q == 0) bVcut[b * NTAG + j] = bj;
    }
  } else {
    // ---- backward sum-product, t = 511..256 ----
    f32x16 ec;  // ROW chunk: ec[i2] = exp(trans[j][16q+i2])
#pragma unroll
    for (int i2 = 0; i2 < 16; ++i2)
      ec[i2] = expf(trans[(size_t)j * NTAG + 16 * q + i2]);

    float bj = expf(endv[j]);  // bLin_511
    float C = 0.f;
    if (q == 0) zbuf[0][j] = bj * expf(sc[(size_t)511 * NTAG + j]);  // g_511
    float e0 = sc[(size_t)510 * NTAG + j], e1 = sc[(size_t)509 * NTAG + j];
    float e2 = sc[(size_t)508 * NTAG + j], e3 = sc[(size_t)507 * NTAG + j];
    int k0 = maskb[511], k1 = maskb[510], k2 = maskb[509], k3 = maskb[508];
    float pe = expf(e0);  // exp(e_{t-1}) for t=511
    __syncthreads();

    int cur = 0;
    for (int t = 511; t >= 257; --t) {
      const float4 z0 = *reinterpret_cast<const float4*>(&zbuf[cur][q * 16 + 0]);
      const float4 z1 = *reinterpret_cast<const float4*>(&zbuf[cur][q * 16 + 4]);
      const float4 z2 = *reinterpret_cast<const float4*>(&zbuf[cur][q * 16 + 8]);
      const float4 z3 = *reinterpret_cast<const float4*>(&zbuf[cur][q * 16 + 12]);
      const float pec = pe;  // exp(e_{t-1})
      const int m = k0;      // m_t
      const int tpe = (t - 5 >= 0) ? (t - 5) : 0;
      const int tpk = (t - 4 >= 256) ? (t - 4) : 256;
      e0 = e1; e1 = e2; e2 = e3;
      e3 = sc[(size_t)tpe * NTAG + j];
      k0 = k1; k1 = k2; k2 = k3;
      k3 = maskb[tpk];
      pe = expf(e0);

      float s0 = z0.x * ec[0], s1 = z0.y * ec[1];
      float s2 = z0.z * ec[2], s3 = z0.w * ec[3];
      s0 = fmaf(z1.x, ec[4], s0);  s1 = fmaf(z1.y, ec[5], s1);
      s2 = fmaf(z1.z, ec[6], s2);  s3 = fmaf(z1.w, ec[7], s3);
      s0 = fmaf(z2.x, ec[8], s0);  s1 = fmaf(z2.y, ec[9], s1);
      s2 = fmaf(z2.z, ec[10], s2); s3 = fmaf(z2.w, ec[11], s3);
      s0 = fmaf(z3.x, ec[12], s0); s1 = fmaf(z3.y, ec[13], s1);
      s2 = fmaf(z3.z, ec[14], s2); s3 = fmaf(z3.w, ec[15], s3);
      float s = (s0 + s1) + (s2 + s3);
      s += quad_xor1(s);
      s += quad_xor2(s);

      bj = m ? s : bj;  // bLin_{t-1}

      if ((t & 7) == 0) {
        const float ws = dpp_red_sum(bj);
        if (lane == 0) part[wv] = ws;
        block_sync_lds();
        const float S4 = (part[0] + part[1]) + (part[2] + part[3]);
        const float r = __builtin_amdgcn_rcpf(S4);
        bj *= 4.0f * r;
        C += logf(S4) - 1.3862943611198906f;
      }

      const int nxt = cur ^ 1;
      if (q == 0) zbuf[nxt][j] = bj * pec;  // g_{t-1}
      block_sync_lds();
      cur = nxt;
    }
    // epilogue t=256 -> bLin_255 (k0 = m_256)
    {
      const float4 z0 = *reinterpret_cast<const float4*>(&zbuf[cur][q * 16 + 0]);
      const float4 z1 = *reinterpret_cast<const float4*>(&zbuf[cur][q * 16 + 4]);
      const float4 z2 = *reinterpret_cast<const float4*>(&zbuf[cur][q * 16 + 8]);
      const float4 z3 = *reinterpret_cast<const float4*>(&zbuf[cur][q * 16 + 12]);
      float s0 = z0.x * ec[0], s1 = z0.y * ec[1];
      float s2 = z0.z * ec[2], s3 = z0.w * ec[3];
      s0 = fmaf(z1.x, ec[4], s0);  s1 = fmaf(z1.y, ec[5], s1);
      s2 = fmaf(z1.z, ec[6], s2);  s3 = fmaf(z1.w, ec[7], s3);
      s0 = fmaf(z2.x, ec[8], s0);  s1 = fmaf(z2.y, ec[9], s1);
      s2 = fmaf(z2.z, ec[10], s2); s3 = fmaf(z2.w, ec[11], s3);
      s0 = fmaf(z3.x, ec[12], s0); s1 = fmaf(z3.y, ec[13], s1);
      s2 = fmaf(z3.z, ec[14], s2); s3 = fmaf(z3.w, ec[15], s3);
      float s = (s0 + s1) + (s2 + s3);
      s += quad_xor1(s);
      s += quad_xor2(s);
      bj = k0 ? s : bj;  // bLin_255
      if (q == 0) bScut[b * NTAG + j] = bj;
      if (tid == 0) Cb[b] = C;
    }
  }
}

// ---------------- Kernel 3: backtrack + loss (fused; 192 blocks) ---------
// role 0: prefix backtrack (jstar computed inline from wsA[255]+bVcut)
// role 1: suffix backtrack (same inline jstar)
// role 2: per-batch loss -> atomicAdd into out_loss (zeroed by gemm).
// Absorbs crf_combine + loss_mean: 6 launches -> 4. Loss blocks run
// concurrently with the serial backtrack chains (192 blocks < 256 CUs).
__global__ __launch_bounds__(64, 1) void viterbi_bt(
    const float* __restrict__ ws_alpha, const float* __restrict__ ws_beta,
    const float* __restrict__ bVcut, const int* __restrict__ mask,
    const float* __restrict__ scores, const float* __restrict__ trans,
    const int* __restrict__ labels, const float* __restrict__ startv,
    const float* __restrict__ endv, const float* __restrict__ zAcut,
    const float* __restrict__ bScut, const float* __restrict__ Ca,
    const float* __restrict__ Cb, float* __restrict__ out_tags,
    float* __restrict__ out_loss) {
  __shared__ float tP[NTAG * 65];  // tP[i*65+j] = trans[i][j]
  __shared__ int mk[256];
  __shared__ unsigned char tagb[256];
  const int lane = threadIdx.x;
  const int role = blockIdx.x >> 6;
  const int b = blockIdx.x & 63;

  if (role == 2) {
    // ---- per-batch loss (old crf_combine body, loss_mean via atomic) ----
    const float* sc = scores + (size_t)b * TT * NTAG;
    const int* maskb = mask + b * TT;
    const float S = dpp_red_sum(zAcut[b * NTAG + lane] * bScut[b * NTAG + lane]);
    const float log_z = logf(S) + Ca[b] + Cb[b];

    float g = 0.f, msumf = 0.f;
    for (int t = lane; t < TT; t += 64) {
      const int lab = labels[b * TT + t];
      const float mf = (float)maskb[t];
      msumf += mf;
      g += sc[(size_t)t * NTAG + lab] * mf;
      if (t >= 1) {
        const int labp = labels[b * TT + t - 1];
        g += trans[(size_t)labp * NTAG + lab] * mf;
      }
    }
    g = dpp_red_sum(g);
    const float msum = dpp_red_sum(msumf);
    const int last_idx = (int)msum - 1;
    g += startv[labels[b * TT]] + endv[labels[b * TT + last_idx]];
    if (lane == 0) atomicAdd(out_loss, (log_z - g) * (1.0f / 64.0f));
    return;
  }

#pragma unroll
  for (int i = 0; i < NTAG; ++i) tP[i * 65 + lane] = trans[(size_t)i * NTAG + lane];
  const int tbase = role * 256;
  for (int t = lane; t < 256; t += 64) mk[t] = mask[b * TT + tbase + t];
  __syncthreads();

  // jstar at the cut (inline; removes combine->bt dependency)
  const float* wsA = ws_alpha + (size_t)b * 256 * NTAG;
  const float fv = wsA[(size_t)255 * NTAG + lane] + bVcut[b * NTAG + lane];
  const float mx = dpp_red_max(fv);
  int jcur = (int)__builtin_ctzll(__ballot(fv == mx));

  if (role == 0) {
    // prefix: tag_255 = jstar; s = 254..0 via alpha_s
    if (lane == 0) tagb[255] = (unsigned char)jcur;

    float a0 = wsA[(size_t)254 * NTAG + lane];
    float a1 = wsA[(size_t)253 * NTAG + lane];
    float a2 = wsA[(size_t)252 * NTAG + lane];
    float a3 = wsA[(size_t)251 * NTAG + lane];

    for (int s = 254; s >= 0; --s) {
      const float ac = a0;  // alpha_s
      a0 = a1; a1 = a2; a2 = a3;
      const int sp = (s >= 4) ? (s - 4) : 0;
      a3 = wsA[(size_t)sp * NTAG + lane];
      if (mk[s + 1]) {
        const float c = ac + tP[lane * 65 + jcur];
        const float cmx = dpp_red_max(c);
        jcur = (int)__builtin_ctzll(__ballot(c == cmx));
      }
      if (lane == 0) tagb[s] = (unsigned char)jcur;
    }
  } else {
    // suffix: t = 256..511; candidates per lane k = lane
    const float* wsB = ws_beta + (size_t)b * 256 * NTAG;
    const float* scb = scores + (size_t)b * TT * NTAG;
    float r0 = wsB[(size_t)0 * NTAG + lane], r1 = wsB[(size_t)1 * NTAG + lane];
    float r2 = wsB[(size_t)2 * NTAG + lane], r3 = wsB[(size_t)3 * NTAG + lane];
    float s0 = scb[(size_t)256 * NTAG + lane], s1 = scb[(size_t)257 * NTAG + lane];
    float s2 = scb[(size_t)258 * NTAG + lane], s3 = scb[(size_t)259 * NTAG + lane];

    for (int t = 256; t < TT; ++t) {
      const float bv = r0, sv = s0;
      const int tb = (t + 4 < TT) ? (t + 4) : (TT - 1);
      r0 = r1; r1 = r2; r2 = r3;
      r3 = wsB[(size_t)(tb - 256) * NTAG + lane];
      s0 = s1; s1 = s2; s2 = s3;
      s3 = scb[(size_t)tb * NTAG + lane];
      if (mk[t - 256]) {
        const float c = tP[jcur * 65 + lane] + sv + bv;
        const float cmx = dpp_red_max(c);
        jcur = (int)__builtin_ctzll(__ballot(c == cmx));
      }
      if (lane == 0) tagb[t - 256] = (unsigned char)jcur;
    }
  }
  __syncthreads();
  for (int t = lane; t < 256; t += 64)
    out_tags[b * TT + tbase + t] = (float)(mk[t] ? (int)tagb[t] : 0);
}

extern "C" void kernel_launch(void* const* d_in, const int* in_sizes, int n_in,
                              void* d_out, int out_size, void* d_ws, size_t ws_size,
                              hipStream_t stream) {
  const float* X = (const float*)d_in[0];
  const int* mask = (const int*)d_in[1];
  const int* labels = (const int*)d_in[2];
  const float* W = (const float*)d_in[3];
  const float* bias = (const float*)d_in[4];
  const float* trans = (const float*)d_in[5];
  const float* startv = (const float*)d_in[6];
  const float* endv = (const float*)d_in[7];

  float* out = (float*)d_out;
  float* scores = out;
  float* out_tags = out + TAGS_OFF;
  float* out_loss = out + LOSS_OFF;

  unsigned short* wf_hi = (unsigned short*)d_ws;            // 65536 bf16
  unsigned short* wf_lo = wf_hi + 65536;                    // 65536 bf16
  float* ws_alpha = (float*)(wf_lo + 65536);                // 64*256*64 fp32
  float* ws_beta = ws_alpha + (size_t)BB * 256 * NTAG;      // 64*256*64 fp32
  float* zAcut = ws_beta + (size_t)BB * 256 * NTAG;         // 64*64
  float* bScut = zAcut + BB * NTAG;                         // 64*64
  float* bVcut = bScut + BB * NTAG;                         // 64*64
  float* Ca = bVcut + BB * NTAG;                            // 64
  float* Cb = Ca + BB;                                      // 64

  prep_w<<<32, 256, 0, stream>>>(W, wf_hi, wf_lo);
  gemm_scores<<<1024, 256, 0, stream>>>(X, mask, wf_hi, wf_lo, bias, scores,
                                        out_loss);
  crf_forward<<<256, 256, 0, stream>>>(scores, mask, trans, startv, endv,
                                       ws_alpha, ws_beta, zAcut, bScut, bVcut,
                                       Ca, Cb);
  viterbi_bt<<<192, 64, 0, stream>>>(ws_alpha, ws_beta, bVcut, mask, scores,
                                     trans, labels, startv, endv, zAcut, bScut,
                                     Ca, Cb, out_tags, out_loss);
}